// Round 1
// baseline (402.810 us; speedup 1.0000x reference)
//
#include <hip/hip_runtime.h>
#include <math.h>

// Problem constants
#define BROWS 16384
#define N0    2048
#define NCLS  12
#define NCLU  24
#define NDIM  4
#define NCOL  348          // 12 + 288 + 48
#define NPAD  384          // padded fused-column count (24 col-tiles of 16)
#define NTILE 24           // NPAD/16

// Output offsets (floats): y0 [B,12] | y1_sel [B,24] | y2_sel [B,4] | Plc [B,24,12]
#define OUT0_OFF 0
#define OUT1_OFF (BROWS * NCLS)
#define OUT2_OFF (OUT1_OFF + BROWS * NCLU)
#define OUT3_OFF (OUT2_OFF + BROWS * NDIM)

typedef __attribute__((ext_vector_type(8))) short bf16x8;
typedef __attribute__((ext_vector_type(4))) float f32x4;
typedef unsigned short ushort_t;

// ---------------------------------------------------------------------------
// bf16 helpers — RNE split (bit-identical to the passing numerics)
// ---------------------------------------------------------------------------
__device__ __forceinline__ unsigned short f2bf(float f) {   // RNE
    unsigned u = __float_as_uint(f);
    u += 0x7fffu + ((u >> 16) & 1u);
    return (unsigned short)(u >> 16);
}
__device__ __forceinline__ float bf2f(unsigned short h) {
    return __uint_as_float(((unsigned)h) << 16);
}
__device__ __forceinline__ void cvt8(float4 a, float4 b, bf16x8& h, bf16x8& l) {
    float f[8] = {a.x, a.y, a.z, a.w, b.x, b.y, b.z, b.w};
    #pragma unroll
    for (int i = 0; i < 8; ++i) {
        unsigned short hi = f2bf(f[i]);
        h[i] = (short)hi;
        l[i] = (short)f2bf(f[i] - bf2f(hi));
    }
}

__device__ __forceinline__ void load_lds16(const void* g, void* l) {
    __builtin_amdgcn_global_load_lds((const __attribute__((address_space(1))) void*)g,
                                     (__attribute__((address_space(3))) void*)l, 16, 0, 0);
}

__device__ __forceinline__ float fused_w(const float* __restrict__ W_fc,
                                         const float* __restrict__ W_bin,
                                         const float* __restrict__ W_res,
                                         int col, int d) {
    float w = 0.0f;
    if (col < NCLS) {
        w = W_fc[d * NCLS + col];
    } else if (col < 12 + NCLU * NCLS) {
        int jj = col - 12;
        int k = jj / NCLS, c = jj - k * NCLS;
        w = W_bin[((size_t)c * N0 + d) * NCLU + k];
    } else if (col < NCOL) {
        int jj = col - 300;
        int n = jj / NCLS, c = jj - n * NCLS;
        w = W_res[((size_t)c * N0 + d) * NDIM + n];
    }
    return w;
}

// ---------------------------------------------------------------------------
// Kernel 1: repack fused weights straight into MFMA-fragment streaming order.
//   Bp{h,l}[((J*64 + kb)*64 + lane)*8 + i] = W[col = J*16 + (lane&15)]
//                                             [k  = kb*32 + (lane>>4)*8 + i]
// ---------------------------------------------------------------------------
__global__ void jcp_repack3(const float* __restrict__ W_fc, const float* __restrict__ b_fc,
                            const float* __restrict__ W_bin, const float* __restrict__ b_bin,
                            const float* __restrict__ W_res, const float* __restrict__ b_res,
                            ushort_t* __restrict__ Bph, ushort_t* __restrict__ Bpl,
                            float* __restrict__ bias) {
    int t = blockIdx.x * 256 + threadIdx.x;          // 0 .. 98303
    if (t >= NTILE * 64 * 64) return;
    const int lane = t & 63;
    const int kb   = (t >> 6) & 63;
    const int J    = t >> 12;
    const int col  = J * 16 + (lane & 15);
    const int k0   = kb * 32 + (lane >> 4) * 8;

    bf16x8 h, l;
    #pragma unroll
    for (int i = 0; i < 8; ++i) {
        float w = fused_w(W_fc, W_bin, W_res, col, k0 + i);
        unsigned short hi = f2bf(w);
        h[i] = (short)hi;
        l[i] = (short)f2bf(w - bf2f(hi));
    }
    *(bf16x8*)(Bph + (size_t)t * 8) = h;
    *(bf16x8*)(Bpl + (size_t)t * 8) = l;

    if (t < NPAD) {
        int jb = t;
        float bv = 0.0f;
        if (jb < NCLS) {
            bv = b_fc[jb];
        } else if (jb < 12 + NCLU * NCLS) {
            int jj = jb - 12;
            int k = jj / NCLS, c = jj - k * NCLS;
            bv = b_bin[c * NCLU + k];
        } else if (jb < NCOL) {
            int jj = jb - 300;
            int n = jj / NCLS, c = jj - n * NCLS;
            bv = b_res[c * NDIM + n];
        }
        bias[jb] = bv;
    }
}

// ---------------------------------------------------------------------------
// Kernel 1b: one-shot split-bf16 conversion of x (bit-identical to in-loop cvt8).
//   Xc layout: [row][kb 0..63][ 32 x hi bf16 | 32 x lo bf16 ]  (128 B per kb)
//   Thread -> one k-octet: read 32 B fp32, write 16 B hi + 16 B lo.
//   Grid-stride: 4096 blocks x 256 thr x 4 iters = 4,194,304 octets.
// ---------------------------------------------------------------------------
__global__ __launch_bounds__(256) void jcp_xcvt(const float* __restrict__ x,
                                                ushort_t* __restrict__ Xc) {
    const int t0 = blockIdx.x * 256 + threadIdx.x;
    #pragma unroll
    for (int i = 0; i < 4; ++i) {
        const size_t t = (size_t)t0 + (size_t)i * 1048576;   // stride = total threads
        const float4 a = *(const float4*)(x + t * 8);
        const float4 b = *(const float4*)(x + t * 8 + 4);
        bf16x8 h, l;
        cvt8(a, b, h, l);
        const size_t r  = t >> 8;          // row (256 octets per row)
        const int    oc = (int)(t & 255);
        const int    kb = oc >> 2, o = oc & 3;
        ushort_t* dst = Xc + (r * 64 + kb) * 64;
        *(bf16x8*)(dst + o * 8)      = h;
        *(bf16x8*)(dst + 32 + o * 8) = l;
    }
}

// ---------------------------------------------------------------------------
// Kernel 2 (new): split-bf16 MFMA GEMM v5 — no cvt in the loop.
//   Grid 2048 (1D, XCD-bijective swizzle), block 256 = 4 waves.
//   Block tile: 64 rows x 48 cols; wave = one 16-row tile, all 3 col-tiles
//   (all 4 waves share B fragments -> L1 reuse). 8 blocks/CU resident.
//   x: pre-split bf16 (Xc) -> LDS via global_load_lds (dbuf 2x8KB), XOR chunk
//      swizzle (o = c ^ (row&7)) on the GLOBAL source; reads apply same XOR.
// ---------------------------------------------------------------------------
__global__ __launch_bounds__(256, 8) void jcp_gemm5(const ushort_t* __restrict__ Xc,
                                                    const ushort_t* __restrict__ Bph,
                                                    const ushort_t* __restrict__ Bpl,
                                                    const float* __restrict__ bias,
                                                    float* __restrict__ Y) {
    __shared__ ushort_t Lx[2 * 4096];    // 2 bufs x 64 rows x (32 hi | 32 lo) = 8 KB each

    const int tid  = threadIdx.x;
    const int wid  = tid >> 6;
    const int lane = tid & 63;
    const int quad = lane >> 4;
    const int l16  = lane & 15;

    // XCD-bijective decode: the 8 col-blocks of a row-panel share one XCD's L2.
    const int g   = blockIdx.x;          // 0..2047, nwg % 8 == 0 -> bijective
    const int xcd = g & 7;
    const int jj  = g >> 3;              // 0..255
    const int by  = xcd * 32 + (jj >> 3);
    const int bx  = jj & 7;
    const int rbase = by * 64;
    const int jbase = bx * 48;
    const int wrow  = wid * 16;

    // --- DMA source addresses (2 insts/thread: rows r0 and r0+32) ---
    const int r0 = tid >> 3;             // 0..31
    const int c0 = tid & 7;
    const int o0 = c0 ^ (r0 & 7);        // pre-swizzled source chunk ((r0+32)&7 == r0&7)
    const ushort_t* gsrc0 = Xc + (size_t)(rbase + r0) * 4096 + o0 * 8;
    const ushort_t* gsrc1 = gsrc0 + (size_t)32 * 4096;
    const int ldst0 = tid * 8;           // ushort offset: linear, lane x 16B
    const int ldst1 = ldst0 + 2048;

    // --- fragment read offset (ushort units); Al = Ah ^ chunk-bit-2 (XOR 32) ---
    const int R     = wrow + l16;
    const int haddr = R * 64 + ((quad ^ (R & 7)) << 3);

    // --- B per-lane pointers, fragment-order arrays ---
    const ushort_t* pBh = Bph + (size_t)lane * 8;
    const ushort_t* pBl = Bpl + (size_t)lane * 8;
    int Jt[3];
    #pragma unroll
    for (int j = 0; j < 3; ++j) Jt[j] = (bx * 3 + j) * 32768;

    f32x4 acc[3];
    #pragma unroll
    for (int j = 0; j < 3; ++j) acc[j] = f32x4{0.f, 0.f, 0.f, 0.f};

    // stage it=0 into buf 0 (barrier's vmcnt(0) drain completes the DMA)
    load_lds16(gsrc0, &Lx[ldst0]);
    load_lds16(gsrc1, &Lx[ldst1]);
    __syncthreads();

    int p = 0;
    for (int it = 0; it < 64; ++it) {
        // issue next-tile DMA first (latency-critical for the end-of-iter barrier)
        if (it < 63) {
            load_lds16(gsrc0 + (it + 1) * 64, &Lx[(p ^ 1) * 4096 + ldst0]);
            load_lds16(gsrc1 + (it + 1) * 64, &Lx[(p ^ 1) * 4096 + ldst1]);
        }
        // B fragments (L2/L1-resident, coalesced; identical for all 4 waves)
        bf16x8 bh[3], bl[3];
        #pragma unroll
        for (int j = 0; j < 3; ++j) {
            bh[j] = *(const bf16x8*)(pBh + Jt[j] + it * 512);
            bl[j] = *(const bf16x8*)(pBl + Jt[j] + it * 512);
        }
        // A fragments: direct bf16 ds_read_b128 — no cvt
        const ushort_t* lb = &Lx[p * 4096];
        bf16x8 Ah = *(const bf16x8*)(lb + haddr);
        bf16x8 Al = *(const bf16x8*)(lb + (haddr ^ 32));

        // 9 MFMAs: per-accumulator order hh -> lh -> hl (bit-identical)
        #pragma unroll
        for (int j = 0; j < 3; ++j) {
            acc[j] = __builtin_amdgcn_mfma_f32_16x16x32_bf16(Ah, bh[j], acc[j], 0, 0, 0);
            acc[j] = __builtin_amdgcn_mfma_f32_16x16x32_bf16(Al, bh[j], acc[j], 0, 0, 0);
            acc[j] = __builtin_amdgcn_mfma_f32_16x16x32_bf16(Ah, bl[j], acc[j], 0, 0, 0);
        }
        __syncthreads();   // drains DMA (vmcnt(0)) + guards buffer reuse
        p ^= 1;
    }

    // Epilogue: C/D layout col = lane&15, row = quad*4 + reg
    #pragma unroll
    for (int j = 0; j < 3; ++j) {
        const int col = jbase + 16 * j + l16;
        const float bj = bias[col];
        float* yp = Y + (size_t)(rbase + wrow + quad * 4) * NPAD + col;
        yp[0 * NPAD] = acc[j][0] + bj;
        yp[1 * NPAD] = acc[j][1] + bj;
        yp[2 * NPAD] = acc[j][2] + bj;
        yp[3 * NPAD] = acc[j][3] + bj;
    }
}

// ---------------------------------------------------------------------------
// Kernel 2 (fallback, proven): split-bf16 MFMA GEMM v4 with in-loop cvt.
// Used only if the workspace cannot hold Xc. Bit-identical outputs.
// ---------------------------------------------------------------------------
__global__ __launch_bounds__(256, 4) void jcp_gemm4(const float* __restrict__ x,
                                                    const ushort_t* __restrict__ Bph,
                                                    const ushort_t* __restrict__ Bpl,
                                                    const float* __restrict__ bias,
                                                    float* __restrict__ Y) {
    __shared__ float Lx[2 * 2048];    // 2 bufs x 64 rows x 32 floats (8 KB each)

    const int tid  = threadIdx.x;
    const int wid  = tid >> 6;
    const int lane = tid & 63;
    const int quad = lane >> 4;
    const int l16  = lane & 15;
    const int wrow = (wid & 1) * 32;          // row half
    const int wct  = (wid >> 1) * 3;          // first col-tile (of 6 in block)
    const int rbase = blockIdx.y * 64;
    const int jbase = blockIdx.x * 96;

    const int dr = lane >> 3;                 // 0..7 row within inst
    const int dc = (lane & 7) ^ dr;           // swizzled chunk (16B units)
    const float* gsrc0 = x + (size_t)(rbase + 8 * (2 * wid) + dr) * N0 + dc * 4;
    const float* gsrc1 = x + (size_t)(rbase + 8 * (2 * wid + 1) + dr) * N0 + dc * 4;
    const int ldst0 = (2 * wid) * 256;
    const int ldst1 = (2 * wid + 1) * 256;

    const int s = l16 & 7;
    const int pos1 = (2 * quad) ^ s;
    const int o1 = pos1 * 4;
    const int o2 = (pos1 ^ 1) * 4;
    const int ro0 = (wrow + l16) * 32;
    const int ro1 = (wrow + 16 + l16) * 32;

    const ushort_t* pBh = Bph + (size_t)lane * 8;
    const ushort_t* pBl = Bpl + (size_t)lane * 8;
    int Jt[3];
    #pragma unroll
    for (int j = 0; j < 3; ++j) Jt[j] = (jbase / 16 + wct + j) * 32768;

    f32x4 acc[2][3];
    #pragma unroll
    for (int i = 0; i < 2; ++i)
        #pragma unroll
        for (int j = 0; j < 3; ++j)
            acc[i][j] = f32x4{0.f, 0.f, 0.f, 0.f};

    load_lds16(gsrc0, &Lx[ldst0]);
    load_lds16(gsrc1, &Lx[ldst1]);
    __syncthreads();

    int p = 0;
    for (int it = 0; it < 64; ++it) {
        bf16x8 bh[3], bl[3];
        #pragma unroll
        for (int j = 0; j < 3; ++j) {
            bh[j] = *(const bf16x8*)(pBh + Jt[j] + it * 512);
            bl[j] = *(const bf16x8*)(pBl + Jt[j] + it * 512);
        }
        if (it < 63) {
            load_lds16(gsrc0 + (it + 1) * 32, &Lx[(p ^ 1) * 2048 + ldst0]);
            load_lds16(gsrc1 + (it + 1) * 32, &Lx[(p ^ 1) * 2048 + ldst1]);
        }
        const int pb = p * 2048;
        float4 f0a = *(const float4*)&Lx[pb + ro0 + o1];
        float4 f0b = *(const float4*)&Lx[pb + ro0 + o2];
        float4 f1a = *(const float4*)&Lx[pb + ro1 + o1];
        float4 f1b = *(const float4*)&Lx[pb + ro1 + o2];
        bf16x8 Ah[2], Al[2];
        cvt8(f0a, f0b, Ah[0], Al[0]);
        cvt8(f1a, f1b, Ah[1], Al[1]);

        #pragma unroll
        for (int j = 0; j < 3; ++j)
            #pragma unroll
            for (int i = 0; i < 2; ++i) {
                acc[i][j] = __builtin_amdgcn_mfma_f32_16x16x32_bf16(Ah[i], bh[j], acc[i][j], 0, 0, 0);
                acc[i][j] = __builtin_amdgcn_mfma_f32_16x16x32_bf16(Al[i], bh[j], acc[i][j], 0, 0, 0);
                acc[i][j] = __builtin_amdgcn_mfma_f32_16x16x32_bf16(Ah[i], bl[j], acc[i][j], 0, 0, 0);
            }
        __syncthreads();
        p ^= 1;
    }

    #pragma unroll
    for (int j = 0; j < 3; ++j) {
        const int col = jbase + wct * 16 + 16 * j + l16;
        const float bj = bias[col];
        #pragma unroll
        for (int i = 0; i < 2; ++i) {
            float* yp = Y + (size_t)(rbase + wrow + i * 16 + quad * 4) * NPAD + col;
            yp[0 * NPAD] = acc[i][j][0] + bj;
            yp[1 * NPAD] = acc[i][j][1] + bj;
            yp[2 * NPAD] = acc[i][j][2] + bj;
            yp[3 * NPAD] = acc[i][j][3] + bj;
        }
    }
}

// ---------------------------------------------------------------------------
// Kernel 3: head. Block = 256 thr = 16 rows x 16 lanes (lane = class).
// ---------------------------------------------------------------------------
#define LROW 388   // padded LDS row stride (floats)

__global__ __launch_bounds__(256) void jcp_head3(const float* __restrict__ Y,
                                                 float* __restrict__ out) {
    __shared__ float Ly[16 * LROW];
    const int tid = threadIdx.x;
    const int r0  = blockIdx.x * 16;

    #pragma unroll
    for (int jj = 0; jj < 6; ++jj) {
        int f = tid + jj * 256;
        int row = f / 96, c4 = f - row * 96;
        float4 v = *(const float4*)(Y + (size_t)(r0 + row) * NPAD + c4 * 4);
        *(float4*)&Ly[row * LROW + c4 * 4] = v;
    }
    __syncthreads();

    const int grp = tid >> 4;
    const int c   = tid & 15;
    const bool on = (c < NCLS);
    const int r   = r0 + grp;
    const float* y = &Ly[grp * LROW];

    float y0c = on ? y[c] : -INFINITY;
    float m0 = y0c;
    #pragma unroll
    for (int m = 8; m >= 1; m >>= 1) m0 = fmaxf(m0, __shfl_xor(m0, m, 16));
    float e0 = on ? expf(y0c - m0) : 0.0f;
    float s0 = e0;
    #pragma unroll
    for (int m = 8; m >= 1; m >>= 1) s0 += __shfl_xor(s0, m, 16);
    const float Pc = e0 / s0;

    float v[NCLU];
    float mc = -INFINITY;
    #pragma unroll
    for (int k = 0; k < NCLU; ++k) {
        v[k] = y[12 + k * NCLS + c];
        mc = fmaxf(mc, v[k]);
    }
    float sc = 0.0f;
    #pragma unroll
    for (int k = 0; k < NCLU; ++k) sc += expf(v[k] - mc);
    const float rs = Pc / sc;

    float y2c[NDIM];
    #pragma unroll
    for (int n = 0; n < NDIM; ++n) y2c[n] = y[300 + n * NCLS + c];

    float best = -INFINITY;
    int bk = 0;
    float* lrow = &Ly[grp * LROW];
    #pragma unroll
    for (int k = 0; k < NCLU; ++k) {
        const float p = expf(v[k] - mc) * rs;
        if (on) lrow[k * NCLS + c] = p;
        if (p > best) { best = p; bk = k; }
    }
    int flat = bk * NCLS + c;
    if (!on) { best = -INFINITY; flat = 1 << 30; }

    #pragma unroll
    for (int m = 8; m >= 1; m >>= 1) {
        const float op = __shfl_xor(best, m, 16);
        const int   of = __shfl_xor(flat, m, 16);
        if (op > best || (op == best && of < flat)) { best = op; flat = of; }
    }
    const int ic = flat % NCLS;

    if (on) out[OUT0_OFF + (size_t)r * NCLS + c] = y0c;
    if (c == ic) {
        float* o1 = out + OUT1_OFF + (size_t)r * NCLU;
        #pragma unroll
        for (int k = 0; k < NCLU; ++k) o1[k] = v[k];
        float* o2 = out + OUT2_OFF + (size_t)r * NDIM;
        #pragma unroll
        for (int n = 0; n < NDIM; ++n) o2[n] = y2c[n];
    }

    __syncthreads();
    #pragma unroll
    for (int jj = 0; jj < 5; ++jj) {
        int f = tid + jj * 256;
        if (f < 1152) {
            int row = f / 72, c4 = f - row * 72;
            *(float4*)(out + OUT3_OFF + (size_t)(r0 + row) * (NCLU * NCLS) + c4 * 4) =
                *(float4*)&Ly[row * LROW + c4 * 4];
        }
    }
}

// ---------------------------------------------------------------------------
extern "C" void kernel_launch(void* const* d_in, const int* in_sizes, int n_in,
                              void* d_out, int out_size, void* d_ws, size_t ws_size,
                              hipStream_t stream) {
    const float* x     = (const float*)d_in[0];
    const float* W_fc  = (const float*)d_in[1];
    const float* b_fc  = (const float*)d_in[2];
    const float* W_bin = (const float*)d_in[3];
    const float* b_bin = (const float*)d_in[4];
    const float* W_res = (const float*)d_in[5];
    const float* b_res = (const float*)d_in[6];
    float* out = (float*)d_out;

    // ws layout (bytes):
    //   Bph 1.5MB | Bpl 1.5MB | bias 1.5KB | Y 25.2MB | Xc 134.2MB (fast path)
    ushort_t* Bph  = (ushort_t*)d_ws;                  // 24*64*64*8 bf16 = 1.5 MB
    ushort_t* Bpl  = Bph + NTILE * 64 * 64 * 8;        // 1.5 MB
    float*    bias = (float*)(Bpl + NTILE * 64 * 64 * 8);
    float*    Yb   = bias + NPAD;                      // 16384*384 fp32
    ushort_t* Xc   = (ushort_t*)(Yb + (size_t)BROWS * NPAD);  // 16384*4096 bf16*2 planes

    const size_t need = (size_t)(NTILE * 64 * 64 * 8) * 2 * sizeof(ushort_t)
                      + NPAD * sizeof(float)
                      + (size_t)BROWS * NPAD * sizeof(float)
                      + (size_t)BROWS * 4096 * sizeof(ushort_t);

    jcp_repack3<<<384, 256, 0, stream>>>(W_fc, b_fc, W_bin, b_bin, W_res, b_res,
                                         Bph, Bpl, bias);
    if (ws_size >= need) {
        jcp_xcvt<<<4096, 256, 0, stream>>>(x, Xc);
        jcp_gemm5<<<2048, 256, 0, stream>>>(Xc, Bph, Bpl, bias, Yb);
    } else {
        dim3 grid(NPAD / 96, BROWS / 64);   // (4, 256)
        jcp_gemm4<<<grid, 256, 0, stream>>>(x, Bph, Bpl, bias, Yb);
    }
    jcp_head3<<<BROWS / 16, 256, 0, stream>>>(Yb, out);
}

// Round 2
// 371.496 us; speedup vs baseline: 1.0843x; 1.0843x over previous
//
#include <hip/hip_runtime.h>
#include <math.h>

// Problem constants
#define BROWS 16384
#define N0    2048
#define NCLS  12
#define NCLU  24
#define NDIM  4
#define NCOL  348          // 12 + 288 + 48
#define NPAD  384          // padded fused-column count (24 col-tiles of 16)
#define NTILE 24           // NPAD/16

// Output offsets (floats): y0 [B,12] | y1_sel [B,24] | y2_sel [B,4] | Plc [B,24,12]
#define OUT0_OFF 0
#define OUT1_OFF (BROWS * NCLS)
#define OUT2_OFF (OUT1_OFF + BROWS * NCLU)
#define OUT3_OFF (OUT2_OFF + BROWS * NDIM)

typedef __attribute__((ext_vector_type(8))) short bf16x8;
typedef __attribute__((ext_vector_type(4))) float f32x4;
typedef unsigned short ushort_t;

// ---------------------------------------------------------------------------
// bf16 helpers — RNE split (bit-identical to the passing numerics)
// ---------------------------------------------------------------------------
__device__ __forceinline__ unsigned short f2bf(float f) {   // RNE
    unsigned u = __float_as_uint(f);
    u += 0x7fffu + ((u >> 16) & 1u);
    return (unsigned short)(u >> 16);
}
__device__ __forceinline__ float bf2f(unsigned short h) {
    return __uint_as_float(((unsigned)h) << 16);
}
__device__ __forceinline__ void cvt8(float4 a, float4 b, bf16x8& h, bf16x8& l) {
    float f[8] = {a.x, a.y, a.z, a.w, b.x, b.y, b.z, b.w};
    #pragma unroll
    for (int i = 0; i < 8; ++i) {
        unsigned short hi = f2bf(f[i]);
        h[i] = (short)hi;
        l[i] = (short)f2bf(f[i] - bf2f(hi));
    }
}

__device__ __forceinline__ void load_lds16(const void* g, void* l) {
    __builtin_amdgcn_global_load_lds((const __attribute__((address_space(1))) void*)g,
                                     (__attribute__((address_space(3))) void*)l, 16, 0, 0);
}

__device__ __forceinline__ float fused_w(const float* __restrict__ W_fc,
                                         const float* __restrict__ W_bin,
                                         const float* __restrict__ W_res,
                                         int col, int d) {
    float w = 0.0f;
    if (col < NCLS) {
        w = W_fc[d * NCLS + col];
    } else if (col < 12 + NCLU * NCLS) {
        int jj = col - 12;
        int k = jj / NCLS, c = jj - k * NCLS;
        w = W_bin[((size_t)c * N0 + d) * NCLU + k];
    } else if (col < NCOL) {
        int jj = col - 300;
        int n = jj / NCLS, c = jj - n * NCLS;
        w = W_res[((size_t)c * N0 + d) * NDIM + n];
    }
    return w;
}

// ---------------------------------------------------------------------------
// Kernel 1: repack fused weights straight into MFMA-fragment streaming order.
//   Bp{h,l}[((J*64 + kb)*64 + lane)*8 + i] = W[col = J*16 + (lane&15)]
//                                             [k  = kb*32 + (lane>>4)*8 + i]
// ---------------------------------------------------------------------------
__global__ void jcp_repack3(const float* __restrict__ W_fc, const float* __restrict__ b_fc,
                            const float* __restrict__ W_bin, const float* __restrict__ b_bin,
                            const float* __restrict__ W_res, const float* __restrict__ b_res,
                            ushort_t* __restrict__ Bph, ushort_t* __restrict__ Bpl,
                            float* __restrict__ bias) {
    int t = blockIdx.x * 256 + threadIdx.x;          // 0 .. 98303
    if (t >= NTILE * 64 * 64) return;
    const int lane = t & 63;
    const int kb   = (t >> 6) & 63;
    const int J    = t >> 12;
    const int col  = J * 16 + (lane & 15);
    const int k0   = kb * 32 + (lane >> 4) * 8;

    bf16x8 h, l;
    #pragma unroll
    for (int i = 0; i < 8; ++i) {
        float w = fused_w(W_fc, W_bin, W_res, col, k0 + i);
        unsigned short hi = f2bf(w);
        h[i] = (short)hi;
        l[i] = (short)f2bf(w - bf2f(hi));
    }
    *(bf16x8*)(Bph + (size_t)t * 8) = h;
    *(bf16x8*)(Bpl + (size_t)t * 8) = l;

    if (t < NPAD) {
        int jb = t;
        float bv = 0.0f;
        if (jb < NCLS) {
            bv = b_fc[jb];
        } else if (jb < 12 + NCLU * NCLS) {
            int jj = jb - 12;
            int k = jj / NCLS, c = jj - k * NCLS;
            bv = b_bin[c * NCLU + k];
        } else if (jb < NCOL) {
            int jj = jb - 300;
            int n = jj / NCLS, c = jj - n * NCLS;
            bv = b_res[c * NDIM + n];
        }
        bias[jb] = bv;
    }
}

// ---------------------------------------------------------------------------
// Kernel 1b: one-shot split-bf16 conversion of x (bit-identical to in-loop cvt8).
//   Xc layout: [row][kb 0..63][ 32 x hi bf16 | 32 x lo bf16 ]  (128 B per kb)
// ---------------------------------------------------------------------------
__global__ __launch_bounds__(256) void jcp_xcvt(const float* __restrict__ x,
                                                ushort_t* __restrict__ Xc) {
    const int t0 = blockIdx.x * 256 + threadIdx.x;
    #pragma unroll
    for (int i = 0; i < 4; ++i) {
        const size_t t = (size_t)t0 + (size_t)i * 1048576;   // stride = total threads
        const float4 a = *(const float4*)(x + t * 8);
        const float4 b = *(const float4*)(x + t * 8 + 4);
        bf16x8 h, l;
        cvt8(a, b, h, l);
        const size_t r  = t >> 8;          // row (256 octets per row)
        const int    oc = (int)(t & 255);
        const int    kb = oc >> 2, o = oc & 3;
        ushort_t* dst = Xc + (r * 64 + kb) * 64;
        *(bf16x8*)(dst + o * 8)      = h;
        *(bf16x8*)(dst + 32 + o * 8) = l;
    }
}

// ---------------------------------------------------------------------------
// Kernel 2 (new): split-bf16 MFMA GEMM v6 — big tiles + B staged in LDS.
//   Grid 512 (XCD-bijective: 128 row-panels x 4 col-blocks), block 256 = 4 waves.
//   Block tile: 128 rows x 96 cols; wave = 64x48 (4 row-tiles x 3 col-tiles,
//   36 MFMA/iter, 12 f32x4 acc). 2 blocks/CU (LDS 56 KB).
//   x: Xc -> LDS via global_load_lds (dbuf 2x16KB), XOR chunk swizzle on the
//      pre-swizzled GLOBAL source; frag reads apply the same XOR.
//   B: Bp -> LDS via global_load_lds (dbuf 2x12KB, 12 x 1KB chunks/iter);
//      all 4 waves read fragments with ds_read_b128 (L2 traffic / 4).
// ---------------------------------------------------------------------------
__global__ __launch_bounds__(256, 2) void jcp_gemm6(const ushort_t* __restrict__ Xc,
                                                    const ushort_t* __restrict__ Bph,
                                                    const ushort_t* __restrict__ Bpl,
                                                    const float* __restrict__ bias,
                                                    float* __restrict__ Y) {
    __shared__ ushort_t Lx[2 * 8192];    // 2 bufs x 128 rows x 64 ushorts = 32 KB
    __shared__ ushort_t Lb[2 * 6144];    // 2 bufs x 12 chunks x 512 ushorts = 24 KB

    const int tid  = threadIdx.x;
    const int wid  = tid >> 6;
    const int lane = tid & 63;
    const int quad = lane >> 4;
    const int l16  = lane & 15;
    const int rg   = wid & 1;            // row half of block (64 rows)
    const int cg   = wid >> 1;           // col half of block (48 cols)

    // XCD-bijective decode: 4 col-blocks of a row-panel land on one XCD.
    const int g   = blockIdx.x;          // 0..511, 512 % 8 == 0 -> bijective
    const int xcd = g & 7;
    const int jj  = g >> 3;              // 0..63
    const int by  = xcd * 16 + (jj >> 2);
    const int bx  = jj & 3;
    const int rbase = by * 128;
    const int jbase = bx * 96;

    // --- x DMA: 4 insts/thread, 32 rows each (row r, swizzled chunk) ---
    const int r0 = tid >> 3;             // 0..31
    const int c0 = tid & 7;
    const int o0 = c0 ^ (r0 & 7);        // pre-swizzled source chunk; (r0+32k)&7 == r0&7
    const ushort_t* gx = Xc + (size_t)(rbase + r0) * 4096 + o0 * 8;
    // inst n: src gx + n*32*4096 (+ it*64); dst n*2048 + tid*8

    // --- B DMA: 3 insts/thread; wave w stages chunks w, 4+w, 8+w (1 KB each).
    //     chunk c: col-tile (local) = c>>1, plane = c&1 (0=hi, 1=lo).
    const ushort_t* gb[3];
    int bdst[3];
    #pragma unroll
    for (int m = 0; m < 3; ++m) {
        const int c  = m * 4 + wid;                  // 0..11, wave-uniform
        const int J  = bx * 6 + (c >> 1);            // global col-tile 0..23
        const ushort_t* bp = (c & 1) ? Bpl : Bph;
        gb[m]   = bp + (size_t)J * 32768 + lane * 8; // + it*512 per iter
        bdst[m] = c * 512 + lane * 8;
    }

    // --- A fragment base (ushort units); Al = Ah ^ 32 (chunk-bit-2 swap) ---
    const int abase = (rg * 64 + l16) * 64 + ((quad ^ (l16 & 7)) << 3);

    f32x4 acc[4][3];
    #pragma unroll
    for (int rt = 0; rt < 4; ++rt)
        #pragma unroll
        for (int j = 0; j < 3; ++j)
            acc[rt][j] = f32x4{0.f, 0.f, 0.f, 0.f};

    // stage it=0 into buf 0 (barrier's vmcnt(0) drain completes the DMA)
    #pragma unroll
    for (int n = 0; n < 4; ++n) load_lds16(gx + n * 131072, &Lx[n * 2048 + tid * 8]);
    #pragma unroll
    for (int m = 0; m < 3; ++m) load_lds16(gb[m], &Lb[bdst[m]]);
    __syncthreads();

    int p = 0;
    for (int it = 0; it < 64; ++it) {
        // issue next-tile DMA first (has a full iteration to complete)
        if (it < 63) {
            #pragma unroll
            for (int n = 0; n < 4; ++n)
                load_lds16(gx + n * 131072 + (it + 1) * 64,
                           &Lx[(p ^ 1) * 8192 + n * 2048 + tid * 8]);
            #pragma unroll
            for (int m = 0; m < 3; ++m)
                load_lds16(gb[m] + (it + 1) * 512, &Lb[(p ^ 1) * 6144 + bdst[m]]);
        }
        const ushort_t* lx = &Lx[p * 8192];
        const ushort_t* lb = &Lb[p * 6144];

        // A fragments: 8 x ds_read_b128 (4 row-tiles x hi/lo)
        bf16x8 Ah[4], Al[4];
        #pragma unroll
        for (int rt = 0; rt < 4; ++rt) {
            const int ha = abase + rt * 1024;
            Ah[rt] = *(const bf16x8*)(lx + ha);
            Al[rt] = *(const bf16x8*)(lx + (ha ^ 32));
        }
        // B fragments: 6 x ds_read_b128 (3 col-tiles x hi/lo)
        bf16x8 bh[3], bl[3];
        #pragma unroll
        for (int j = 0; j < 3; ++j) {
            const int ch = (cg * 3 + j) * 2;
            bh[j] = *(const bf16x8*)(lb + ch * 512 + lane * 8);
            bl[j] = *(const bf16x8*)(lb + ch * 512 + 512 + lane * 8);
        }

        // 36 MFMAs: per-accumulator order hh -> lh -> hl (bit-identical)
        #pragma unroll
        for (int j = 0; j < 3; ++j)
            #pragma unroll
            for (int rt = 0; rt < 4; ++rt) {
                acc[rt][j] = __builtin_amdgcn_mfma_f32_16x16x32_bf16(Ah[rt], bh[j], acc[rt][j], 0, 0, 0);
                acc[rt][j] = __builtin_amdgcn_mfma_f32_16x16x32_bf16(Al[rt], bh[j], acc[rt][j], 0, 0, 0);
                acc[rt][j] = __builtin_amdgcn_mfma_f32_16x16x32_bf16(Ah[rt], bl[j], acc[rt][j], 0, 0, 0);
            }
        __syncthreads();   // drains DMA (vmcnt(0)) + guards buffer reuse
        p ^= 1;
    }

    // Epilogue: C/D layout col = lane&15, row = quad*4 + reg
    #pragma unroll
    for (int j = 0; j < 3; ++j) {
        const int col = jbase + cg * 48 + 16 * j + l16;
        const float bj = bias[col];
        #pragma unroll
        for (int rt = 0; rt < 4; ++rt) {
            float* yp = Y + (size_t)(rbase + rg * 64 + rt * 16 + quad * 4) * NPAD + col;
            yp[0 * NPAD] = acc[rt][j][0] + bj;
            yp[1 * NPAD] = acc[rt][j][1] + bj;
            yp[2 * NPAD] = acc[rt][j][2] + bj;
            yp[3 * NPAD] = acc[rt][j][3] + bj;
        }
    }
}

// ---------------------------------------------------------------------------
// Kernel 2 (fallback, proven): split-bf16 MFMA GEMM v4 with in-loop cvt.
// Used only if the workspace cannot hold Xc. Bit-identical outputs.
// ---------------------------------------------------------------------------
__global__ __launch_bounds__(256, 4) void jcp_gemm4(const float* __restrict__ x,
                                                    const ushort_t* __restrict__ Bph,
                                                    const ushort_t* __restrict__ Bpl,
                                                    const float* __restrict__ bias,
                                                    float* __restrict__ Y) {
    __shared__ float Lx[2 * 2048];    // 2 bufs x 64 rows x 32 floats (8 KB each)

    const int tid  = threadIdx.x;
    const int wid  = tid >> 6;
    const int lane = tid & 63;
    const int quad = lane >> 4;
    const int l16  = lane & 15;
    const int wrow = (wid & 1) * 32;          // row half
    const int wct  = (wid >> 1) * 3;          // first col-tile (of 6 in block)
    const int rbase = blockIdx.y * 64;
    const int jbase = blockIdx.x * 96;

    const int dr = lane >> 3;                 // 0..7 row within inst
    const int dc = (lane & 7) ^ dr;           // swizzled chunk (16B units)
    const float* gsrc0 = x + (size_t)(rbase + 8 * (2 * wid) + dr) * N0 + dc * 4;
    const float* gsrc1 = x + (size_t)(rbase + 8 * (2 * wid + 1) + dr) * N0 + dc * 4;
    const int ldst0 = (2 * wid) * 256;
    const int ldst1 = (2 * wid + 1) * 256;

    const int s = l16 & 7;
    const int pos1 = (2 * quad) ^ s;
    const int o1 = pos1 * 4;
    const int o2 = (pos1 ^ 1) * 4;
    const int ro0 = (wrow + l16) * 32;
    const int ro1 = (wrow + 16 + l16) * 32;

    const ushort_t* pBh = Bph + (size_t)lane * 8;
    const ushort_t* pBl = Bpl + (size_t)lane * 8;
    int Jt[3];
    #pragma unroll
    for (int j = 0; j < 3; ++j) Jt[j] = (jbase / 16 + wct + j) * 32768;

    f32x4 acc[2][3];
    #pragma unroll
    for (int i = 0; i < 2; ++i)
        #pragma unroll
        for (int j = 0; j < 3; ++j)
            acc[i][j] = f32x4{0.f, 0.f, 0.f, 0.f};

    load_lds16(gsrc0, &Lx[ldst0]);
    load_lds16(gsrc1, &Lx[ldst1]);
    __syncthreads();

    int p = 0;
    for (int it = 0; it < 64; ++it) {
        bf16x8 bh[3], bl[3];
        #pragma unroll
        for (int j = 0; j < 3; ++j) {
            bh[j] = *(const bf16x8*)(pBh + Jt[j] + it * 512);
            bl[j] = *(const bf16x8*)(pBl + Jt[j] + it * 512);
        }
        if (it < 63) {
            load_lds16(gsrc0 + (it + 1) * 32, &Lx[(p ^ 1) * 2048 + ldst0]);
            load_lds16(gsrc1 + (it + 1) * 32, &Lx[(p ^ 1) * 2048 + ldst1]);
        }
        const int pb = p * 2048;
        float4 f0a = *(const float4*)&Lx[pb + ro0 + o1];
        float4 f0b = *(const float4*)&Lx[pb + ro0 + o2];
        float4 f1a = *(const float4*)&Lx[pb + ro1 + o1];
        float4 f1b = *(const float4*)&Lx[pb + ro1 + o2];
        bf16x8 Ah[2], Al[2];
        cvt8(f0a, f0b, Ah[0], Al[0]);
        cvt8(f1a, f1b, Ah[1], Al[1]);

        #pragma unroll
        for (int j = 0; j < 3; ++j)
            #pragma unroll
            for (int i = 0; i < 2; ++i) {
                acc[i][j] = __builtin_amdgcn_mfma_f32_16x16x32_bf16(Ah[i], bh[j], acc[i][j], 0, 0, 0);
                acc[i][j] = __builtin_amdgcn_mfma_f32_16x16x32_bf16(Al[i], bh[j], acc[i][j], 0, 0, 0);
                acc[i][j] = __builtin_amdgcn_mfma_f32_16x16x32_bf16(Ah[i], bl[j], acc[i][j], 0, 0, 0);
            }
        __syncthreads();
        p ^= 1;
    }

    #pragma unroll
    for (int j = 0; j < 3; ++j) {
        const int col = jbase + wct * 16 + 16 * j + l16;
        const float bj = bias[col];
        #pragma unroll
        for (int i = 0; i < 2; ++i) {
            float* yp = Y + (size_t)(rbase + wrow + i * 16 + quad * 4) * NPAD + col;
            yp[0 * NPAD] = acc[i][j][0] + bj;
            yp[1 * NPAD] = acc[i][j][1] + bj;
            yp[2 * NPAD] = acc[i][j][2] + bj;
            yp[3 * NPAD] = acc[i][j][3] + bj;
        }
    }
}

// ---------------------------------------------------------------------------
// Kernel 3: head. Block = 256 thr = 16 rows x 16 lanes (lane = class).
// ---------------------------------------------------------------------------
#define LROW 388   // padded LDS row stride (floats)

__global__ __launch_bounds__(256) void jcp_head3(const float* __restrict__ Y,
                                                 float* __restrict__ out) {
    __shared__ float Ly[16 * LROW];
    const int tid = threadIdx.x;
    const int r0  = blockIdx.x * 16;

    #pragma unroll
    for (int jj = 0; jj < 6; ++jj) {
        int f = tid + jj * 256;
        int row = f / 96, c4 = f - row * 96;
        float4 v = *(const float4*)(Y + (size_t)(r0 + row) * NPAD + c4 * 4);
        *(float4*)&Ly[row * LROW + c4 * 4] = v;
    }
    __syncthreads();

    const int grp = tid >> 4;
    const int c   = tid & 15;
    const bool on = (c < NCLS);
    const int r   = r0 + grp;
    const float* y = &Ly[grp * LROW];

    float y0c = on ? y[c] : -INFINITY;
    float m0 = y0c;
    #pragma unroll
    for (int m = 8; m >= 1; m >>= 1) m0 = fmaxf(m0, __shfl_xor(m0, m, 16));
    float e0 = on ? expf(y0c - m0) : 0.0f;
    float s0 = e0;
    #pragma unroll
    for (int m = 8; m >= 1; m >>= 1) s0 += __shfl_xor(s0, m, 16);
    const float Pc = e0 / s0;

    float v[NCLU];
    float mc = -INFINITY;
    #pragma unroll
    for (int k = 0; k < NCLU; ++k) {
        v[k] = y[12 + k * NCLS + c];
        mc = fmaxf(mc, v[k]);
    }
    float sc = 0.0f;
    #pragma unroll
    for (int k = 0; k < NCLU; ++k) sc += expf(v[k] - mc);
    const float rs = Pc / sc;

    float y2c[NDIM];
    #pragma unroll
    for (int n = 0; n < NDIM; ++n) y2c[n] = y[300 + n * NCLS + c];

    float best = -INFINITY;
    int bk = 0;
    float* lrow = &Ly[grp * LROW];
    #pragma unroll
    for (int k = 0; k < NCLU; ++k) {
        const float p = expf(v[k] - mc) * rs;
        if (on) lrow[k * NCLS + c] = p;
        if (p > best) { best = p; bk = k; }
    }
    int flat = bk * NCLS + c;
    if (!on) { best = -INFINITY; flat = 1 << 30; }

    #pragma unroll
    for (int m = 8; m >= 1; m >>= 1) {
        const float op = __shfl_xor(best, m, 16);
        const int   of = __shfl_xor(flat, m, 16);
        if (op > best || (op == best && of < flat)) { best = op; flat = of; }
    }
    const int ic = flat % NCLS;

    if (on) out[OUT0_OFF + (size_t)r * NCLS + c] = y0c;
    if (c == ic) {
        float* o1 = out + OUT1_OFF + (size_t)r * NCLU;
        #pragma unroll
        for (int k = 0; k < NCLU; ++k) o1[k] = v[k];
        float* o2 = out + OUT2_OFF + (size_t)r * NDIM;
        #pragma unroll
        for (int n = 0; n < NDIM; ++n) o2[n] = y2c[n];
    }

    __syncthreads();
    #pragma unroll
    for (int jj = 0; jj < 5; ++jj) {
        int f = tid + jj * 256;
        if (f < 1152) {
            int row = f / 72, c4 = f - row * 72;
            *(float4*)(out + OUT3_OFF + (size_t)(r0 + row) * (NCLU * NCLS) + c4 * 4) =
                *(float4*)&Ly[row * LROW + c4 * 4];
        }
    }
}

// ---------------------------------------------------------------------------
extern "C" void kernel_launch(void* const* d_in, const int* in_sizes, int n_in,
                              void* d_out, int out_size, void* d_ws, size_t ws_size,
                              hipStream_t stream) {
    const float* x     = (const float*)d_in[0];
    const float* W_fc  = (const float*)d_in[1];
    const float* b_fc  = (const float*)d_in[2];
    const float* W_bin = (const float*)d_in[3];
    const float* b_bin = (const float*)d_in[4];
    const float* W_res = (const float*)d_in[5];
    const float* b_res = (const float*)d_in[6];
    float* out = (float*)d_out;

    // ws layout (bytes):
    //   Bph 1.5MB | Bpl 1.5MB | bias 1.5KB | Y 25.2MB | Xc 134.2MB (fast path)
    ushort_t* Bph  = (ushort_t*)d_ws;                  // 24*64*64*8 bf16 = 1.5 MB
    ushort_t* Bpl  = Bph + NTILE * 64 * 64 * 8;        // 1.5 MB
    float*    bias = (float*)(Bpl + NTILE * 64 * 64 * 8);
    float*    Yb   = bias + NPAD;                      // 16384*384 fp32
    ushort_t* Xc   = (ushort_t*)(Yb + (size_t)BROWS * NPAD);  // 16384*4096 bf16*2 planes

    const size_t need = (size_t)(NTILE * 64 * 64 * 8) * 2 * sizeof(ushort_t)
                      + NPAD * sizeof(float)
                      + (size_t)BROWS * NPAD * sizeof(float)
                      + (size_t)BROWS * 4096 * sizeof(ushort_t);

    jcp_repack3<<<384, 256, 0, stream>>>(W_fc, b_fc, W_bin, b_bin, W_res, b_res,
                                         Bph, Bpl, bias);
    if (ws_size >= need) {
        jcp_xcvt<<<4096, 256, 0, stream>>>(x, Xc);
        jcp_gemm6<<<512, 256, 0, stream>>>(Xc, Bph, Bpl, bias, Yb);
    } else {
        dim3 grid(NPAD / 96, BROWS / 64);   // (4, 256)
        jcp_gemm4<<<grid, 256, 0, stream>>>(x, Bph, Bpl, bias, Yb);
    }
    jcp_head3<<<BROWS / 16, 256, 0, stream>>>(Yb, out);
}

// Round 3
// 330.386 us; speedup vs baseline: 1.2192x; 1.1244x over previous
//
#include <hip/hip_runtime.h>
#include <math.h>

// Problem constants
#define BROWS 16384
#define N0    2048
#define NCLS  12
#define NCLU  24
#define NDIM  4
#define NCOL  348          // 12 + 288 + 48
#define NPAD  384          // padded fused-column count (24 col-tiles of 16)
#define NTILE 24           // NPAD/16

// Output offsets (floats): y0 [B,12] | y1_sel [B,24] | y2_sel [B,4] | Plc [B,24,12]
#define OUT0_OFF 0
#define OUT1_OFF (BROWS * NCLS)
#define OUT2_OFF (OUT1_OFF + BROWS * NCLU)
#define OUT3_OFF (OUT2_OFF + BROWS * NDIM)

typedef __attribute__((ext_vector_type(8))) short bf16x8;
typedef __attribute__((ext_vector_type(4))) float f32x4;
typedef unsigned short ushort_t;

// ---------------------------------------------------------------------------
// bf16 helpers — RNE split (bit-identical to the passing numerics)
// ---------------------------------------------------------------------------
__device__ __forceinline__ unsigned short f2bf(float f) {   // RNE
    unsigned u = __float_as_uint(f);
    u += 0x7fffu + ((u >> 16) & 1u);
    return (unsigned short)(u >> 16);
}
__device__ __forceinline__ float bf2f(unsigned short h) {
    return __uint_as_float(((unsigned)h) << 16);
}
__device__ __forceinline__ void cvt8(float4 a, float4 b, bf16x8& h, bf16x8& l) {
    float f[8] = {a.x, a.y, a.z, a.w, b.x, b.y, b.z, b.w};
    #pragma unroll
    for (int i = 0; i < 8; ++i) {
        unsigned short hi = f2bf(f[i]);
        h[i] = (short)hi;
        l[i] = (short)f2bf(f[i] - bf2f(hi));
    }
}

__device__ __forceinline__ void load_lds16(const void* g, void* l) {
    __builtin_amdgcn_global_load_lds((const __attribute__((address_space(1))) void*)g,
                                     (__attribute__((address_space(3))) void*)l, 16, 0, 0);
}

__device__ __forceinline__ float fused_w(const float* __restrict__ W_fc,
                                         const float* __restrict__ W_bin,
                                         const float* __restrict__ W_res,
                                         int col, int d) {
    float w = 0.0f;
    if (col < NCLS) {
        w = W_fc[d * NCLS + col];
    } else if (col < 12 + NCLU * NCLS) {
        int jj = col - 12;
        int k = jj / NCLS, c = jj - k * NCLS;
        w = W_bin[((size_t)c * N0 + d) * NCLU + k];
    } else if (col < NCOL) {
        int jj = col - 300;
        int n = jj / NCLS, c = jj - n * NCLS;
        w = W_res[((size_t)c * N0 + d) * NDIM + n];
    }
    return w;
}

// ---------------------------------------------------------------------------
// Kernel 1: repack fused weights straight into MFMA-fragment streaming order.
//   Bp{h,l}[((J*64 + kb)*64 + lane)*8 + i] = W[col = J*16 + (lane&15)]
//                                             [k  = kb*32 + (lane>>4)*8 + i]
// ---------------------------------------------------------------------------
__global__ void jcp_repack3(const float* __restrict__ W_fc, const float* __restrict__ b_fc,
                            const float* __restrict__ W_bin, const float* __restrict__ b_bin,
                            const float* __restrict__ W_res, const float* __restrict__ b_res,
                            ushort_t* __restrict__ Bph, ushort_t* __restrict__ Bpl,
                            float* __restrict__ bias) {
    int t = blockIdx.x * 256 + threadIdx.x;          // 0 .. 98303
    if (t >= NTILE * 64 * 64) return;
    const int lane = t & 63;
    const int kb   = (t >> 6) & 63;
    const int J    = t >> 12;
    const int col  = J * 16 + (lane & 15);
    const int k0   = kb * 32 + (lane >> 4) * 8;

    bf16x8 h, l;
    #pragma unroll
    for (int i = 0; i < 8; ++i) {
        float w = fused_w(W_fc, W_bin, W_res, col, k0 + i);
        unsigned short hi = f2bf(w);
        h[i] = (short)hi;
        l[i] = (short)f2bf(w - bf2f(hi));
    }
    *(bf16x8*)(Bph + (size_t)t * 8) = h;
    *(bf16x8*)(Bpl + (size_t)t * 8) = l;

    if (t < NPAD) {
        int jb = t;
        float bv = 0.0f;
        if (jb < NCLS) {
            bv = b_fc[jb];
        } else if (jb < 12 + NCLU * NCLS) {
            int jj = jb - 12;
            int k = jj / NCLS, c = jj - k * NCLS;
            bv = b_bin[c * NCLU + k];
        } else if (jb < NCOL) {
            int jj = jb - 300;
            int n = jj / NCLS, c = jj - n * NCLS;
            bv = b_res[c * NDIM + n];
        }
        bias[jb] = bv;
    }
}

// ---------------------------------------------------------------------------
// Kernel 1b: one-shot split-bf16 conversion of x (bit-identical to in-loop cvt8).
//   Xc layout: [row][kb 0..63][ 32 x hi bf16 | 32 x lo bf16 ]  (128 B per kb)
// ---------------------------------------------------------------------------
__global__ __launch_bounds__(256) void jcp_xcvt(const float* __restrict__ x,
                                                ushort_t* __restrict__ Xc) {
    const int t0 = blockIdx.x * 256 + threadIdx.x;
    #pragma unroll
    for (int i = 0; i < 4; ++i) {
        const size_t t = (size_t)t0 + (size_t)i * 1048576;   // stride = total threads
        const float4 a = *(const float4*)(x + t * 8);
        const float4 b = *(const float4*)(x + t * 8 + 4);
        bf16x8 h, l;
        cvt8(a, b, h, l);
        const size_t r  = t >> 8;          // row (256 octets per row)
        const int    oc = (int)(t & 255);
        const int    kb = oc >> 2, o = oc & 3;
        ushort_t* dst = Xc + (r * 64 + kb) * 64;
        *(bf16x8*)(dst + o * 8)      = h;
        *(bf16x8*)(dst + 32 + o * 8) = l;
    }
}

// ---------------------------------------------------------------------------
// Kernel 2 (new): split-bf16 MFMA GEMM v7 — gemm6 + counted-vmcnt pipeline (T4).
//   Identical tiling/numerics to gemm6 (128x96 block, 4 waves, 36 MFMA/iter,
//   double-buffered x+B in LDS via global_load_lds). The change: raw
//   s_barrier + counted s_waitcnt vmcnt(7) so the 7 prefetch DMAs for the
//   NEXT buffer stay in flight across the barrier (never drain to 0 in-loop).
//   Schedule per iter: wait vmcnt(7) | barrier | ds_read frags | lgkmcnt(0) |
//   barrier | issue 7 DMAs for it+2 | MFMAs. Last iter peeled with vmcnt(0).
// ---------------------------------------------------------------------------
__global__ __launch_bounds__(256, 2) void jcp_gemm7(const ushort_t* __restrict__ Xc,
                                                    const ushort_t* __restrict__ Bph,
                                                    const ushort_t* __restrict__ Bpl,
                                                    const float* __restrict__ bias,
                                                    float* __restrict__ Y) {
    __shared__ ushort_t Lx[2 * 8192];    // 2 bufs x 128 rows x 64 ushorts = 32 KB
    __shared__ ushort_t Lb[2 * 6144];    // 2 bufs x 12 chunks x 512 ushorts = 24 KB

    const int tid  = threadIdx.x;
    const int wid  = tid >> 6;
    const int lane = tid & 63;
    const int quad = lane >> 4;
    const int l16  = lane & 15;
    const int rg   = wid & 1;            // row half of block (64 rows)
    const int cg   = wid >> 1;           // col half of block (48 cols)

    // XCD-bijective decode: 4 col-blocks of a row-panel land on one XCD.
    const int g   = blockIdx.x;          // 0..511, 512 % 8 == 0 -> bijective
    const int xcd = g & 7;
    const int jj  = g >> 3;              // 0..63
    const int by  = xcd * 16 + (jj >> 2);
    const int bx  = jj & 3;
    const int rbase = by * 128;
    const int jbase = bx * 96;

    // --- x DMA: 4 insts/thread, 32 rows each (row r, swizzled chunk) ---
    const int r0 = tid >> 3;             // 0..31
    const int c0 = tid & 7;
    const int o0 = c0 ^ (r0 & 7);        // pre-swizzled source chunk; (r0+32k)&7 == r0&7
    const ushort_t* gx = Xc + (size_t)(rbase + r0) * 4096 + o0 * 8;
    // inst n: src gx + n*32*4096 (+ it*64); dst n*2048 + tid*8

    // --- B DMA: 3 insts/thread; wave w stages chunks w, 4+w, 8+w (1 KB each).
    //     chunk c: col-tile (local) = c>>1, plane = c&1 (0=hi, 1=lo).
    const ushort_t* gb[3];
    int bdst[3];
    #pragma unroll
    for (int m = 0; m < 3; ++m) {
        const int c  = m * 4 + wid;                  // 0..11, wave-uniform
        const int J  = bx * 6 + (c >> 1);            // global col-tile 0..23
        const ushort_t* bp = (c & 1) ? Bpl : Bph;
        gb[m]   = bp + (size_t)J * 32768 + lane * 8; // + it*512 per iter
        bdst[m] = c * 512 + lane * 8;
    }

    // --- A fragment base (ushort units); Al = Ah ^ 32 (chunk-bit-2 swap) ---
    const int abase = (rg * 64 + l16) * 64 + ((quad ^ (l16 & 7)) << 3);

    f32x4 acc[4][3];
    #pragma unroll
    for (int rt = 0; rt < 4; ++rt)
        #pragma unroll
        for (int j = 0; j < 3; ++j)
            acc[rt][j] = f32x4{0.f, 0.f, 0.f, 0.f};

    // Prologue: issue buf0's 7 DMAs (it=0), then buf1's 7 (it=1).
    #pragma unroll
    for (int n = 0; n < 4; ++n) load_lds16(gx + n * 131072, &Lx[n * 2048 + tid * 8]);
    #pragma unroll
    for (int m = 0; m < 3; ++m) load_lds16(gb[m], &Lb[bdst[m]]);
    #pragma unroll
    for (int n = 0; n < 4; ++n) load_lds16(gx + n * 131072 + 64, &Lx[8192 + n * 2048 + tid * 8]);
    #pragma unroll
    for (int m = 0; m < 3; ++m) load_lds16(gb[m] + 512, &Lb[6144 + bdst[m]]);

    int p = 0;
    for (int it = 0; it < 63; ++it) {
        // Drain only this buffer's 7 loads; next buffer's 7 stay in flight.
        asm volatile("s_waitcnt vmcnt(7)" ::: "memory");
        asm volatile("s_barrier" ::: "memory");          // buf p ready (all waves)

        const ushort_t* lx = &Lx[p * 8192];
        const ushort_t* lb = &Lb[p * 6144];
        bf16x8 Ah[4], Al[4];
        #pragma unroll
        for (int rt = 0; rt < 4; ++rt) {
            const int ha = abase + rt * 1024;
            Ah[rt] = *(const bf16x8*)(lx + ha);
            Al[rt] = *(const bf16x8*)(lx + (ha ^ 32));
        }
        bf16x8 bh[3], bl[3];
        #pragma unroll
        for (int j = 0; j < 3; ++j) {
            const int ch = (cg * 3 + j) * 2;
            bh[j] = *(const bf16x8*)(lb + ch * 512 + lane * 8);
            bl[j] = *(const bf16x8*)(lb + ch * 512 + 512 + lane * 8);
        }
        asm volatile("s_waitcnt lgkmcnt(0)" ::: "memory");   // frags in regs
        asm volatile("s_barrier" ::: "memory");              // all waves done reading p

        // Refill buf p for iteration it+2 (lands while we MFMA + next iter runs).
        if (it < 62) {
            #pragma unroll
            for (int n = 0; n < 4; ++n)
                load_lds16(gx + n * 131072 + (it + 2) * 64,
                           &Lx[p * 8192 + n * 2048 + tid * 8]);
            #pragma unroll
            for (int m = 0; m < 3; ++m)
                load_lds16(gb[m] + (it + 2) * 512, &Lb[p * 6144 + bdst[m]]);
        }

        // 36 MFMAs: per-accumulator order hh -> lh -> hl (bit-identical)
        __builtin_amdgcn_s_setprio(1);
        #pragma unroll
        for (int j = 0; j < 3; ++j)
            #pragma unroll
            for (int rt = 0; rt < 4; ++rt) {
                acc[rt][j] = __builtin_amdgcn_mfma_f32_16x16x32_bf16(Ah[rt], bh[j], acc[rt][j], 0, 0, 0);
                acc[rt][j] = __builtin_amdgcn_mfma_f32_16x16x32_bf16(Al[rt], bh[j], acc[rt][j], 0, 0, 0);
                acc[rt][j] = __builtin_amdgcn_mfma_f32_16x16x32_bf16(Ah[rt], bl[j], acc[rt][j], 0, 0, 0);
            }
        __builtin_amdgcn_s_setprio(0);
        p ^= 1;
    }

    // Peeled last iteration (it = 63, buf p): only its 7 loads remain.
    {
        asm volatile("s_waitcnt vmcnt(0)" ::: "memory");
        asm volatile("s_barrier" ::: "memory");
        const ushort_t* lx = &Lx[p * 8192];
        const ushort_t* lb = &Lb[p * 6144];
        bf16x8 Ah[4], Al[4];
        #pragma unroll
        for (int rt = 0; rt < 4; ++rt) {
            const int ha = abase + rt * 1024;
            Ah[rt] = *(const bf16x8*)(lx + ha);
            Al[rt] = *(const bf16x8*)(lx + (ha ^ 32));
        }
        bf16x8 bh[3], bl[3];
        #pragma unroll
        for (int j = 0; j < 3; ++j) {
            const int ch = (cg * 3 + j) * 2;
            bh[j] = *(const bf16x8*)(lb + ch * 512 + lane * 8);
            bl[j] = *(const bf16x8*)(lb + ch * 512 + 512 + lane * 8);
        }
        #pragma unroll
        for (int j = 0; j < 3; ++j)
            #pragma unroll
            for (int rt = 0; rt < 4; ++rt) {
                acc[rt][j] = __builtin_amdgcn_mfma_f32_16x16x32_bf16(Ah[rt], bh[j], acc[rt][j], 0, 0, 0);
                acc[rt][j] = __builtin_amdgcn_mfma_f32_16x16x32_bf16(Al[rt], bh[j], acc[rt][j], 0, 0, 0);
                acc[rt][j] = __builtin_amdgcn_mfma_f32_16x16x32_bf16(Ah[rt], bl[j], acc[rt][j], 0, 0, 0);
            }
    }

    // Epilogue: C/D layout col = lane&15, row = quad*4 + reg
    #pragma unroll
    for (int j = 0; j < 3; ++j) {
        const int col = jbase + cg * 48 + 16 * j + l16;
        const float bj = bias[col];
        #pragma unroll
        for (int rt = 0; rt < 4; ++rt) {
            float* yp = Y + (size_t)(rbase + rg * 64 + rt * 16 + quad * 4) * NPAD + col;
            yp[0 * NPAD] = acc[rt][j][0] + bj;
            yp[1 * NPAD] = acc[rt][j][1] + bj;
            yp[2 * NPAD] = acc[rt][j][2] + bj;
            yp[3 * NPAD] = acc[rt][j][3] + bj;
        }
    }
}

// ---------------------------------------------------------------------------
// Kernel 2 (fallback, proven): split-bf16 MFMA GEMM v4 with in-loop cvt.
// Used only if the workspace cannot hold Xc. Bit-identical outputs.
// ---------------------------------------------------------------------------
__global__ __launch_bounds__(256, 4) void jcp_gemm4(const float* __restrict__ x,
                                                    const ushort_t* __restrict__ Bph,
                                                    const ushort_t* __restrict__ Bpl,
                                                    const float* __restrict__ bias,
                                                    float* __restrict__ Y) {
    __shared__ float Lx[2 * 2048];    // 2 bufs x 64 rows x 32 floats (8 KB each)

    const int tid  = threadIdx.x;
    const int wid  = tid >> 6;
    const int lane = tid & 63;
    const int quad = lane >> 4;
    const int l16  = lane & 15;
    const int wrow = (wid & 1) * 32;          // row half
    const int wct  = (wid >> 1) * 3;          // first col-tile (of 6 in block)
    const int rbase = blockIdx.y * 64;
    const int jbase = blockIdx.x * 96;

    const int dr = lane >> 3;                 // 0..7 row within inst
    const int dc = (lane & 7) ^ dr;           // swizzled chunk (16B units)
    const float* gsrc0 = x + (size_t)(rbase + 8 * (2 * wid) + dr) * N0 + dc * 4;
    const float* gsrc1 = x + (size_t)(rbase + 8 * (2 * wid + 1) + dr) * N0 + dc * 4;
    const int ldst0 = (2 * wid) * 256;
    const int ldst1 = (2 * wid + 1) * 256;

    const int s = l16 & 7;
    const int pos1 = (2 * quad) ^ s;
    const int o1 = pos1 * 4;
    const int o2 = (pos1 ^ 1) * 4;
    const int ro0 = (wrow + l16) * 32;
    const int ro1 = (wrow + 16 + l16) * 32;

    const ushort_t* pBh = Bph + (size_t)lane * 8;
    const ushort_t* pBl = Bpl + (size_t)lane * 8;
    int Jt[3];
    #pragma unroll
    for (int j = 0; j < 3; ++j) Jt[j] = (jbase / 16 + wct + j) * 32768;

    f32x4 acc[2][3];
    #pragma unroll
    for (int i = 0; i < 2; ++i)
        #pragma unroll
        for (int j = 0; j < 3; ++j)
            acc[i][j] = f32x4{0.f, 0.f, 0.f, 0.f};

    load_lds16(gsrc0, &Lx[ldst0]);
    load_lds16(gsrc1, &Lx[ldst1]);
    __syncthreads();

    int p = 0;
    for (int it = 0; it < 64; ++it) {
        bf16x8 bh[3], bl[3];
        #pragma unroll
        for (int j = 0; j < 3; ++j) {
            bh[j] = *(const bf16x8*)(pBh + Jt[j] + it * 512);
            bl[j] = *(const bf16x8*)(pBl + Jt[j] + it * 512);
        }
        if (it < 63) {
            load_lds16(gsrc0 + (it + 1) * 32, &Lx[(p ^ 1) * 2048 + ldst0]);
            load_lds16(gsrc1 + (it + 1) * 32, &Lx[(p ^ 1) * 2048 + ldst1]);
        }
        const int pb = p * 2048;
        float4 f0a = *(const float4*)&Lx[pb + ro0 + o1];
        float4 f0b = *(const float4*)&Lx[pb + ro0 + o2];
        float4 f1a = *(const float4*)&Lx[pb + ro1 + o1];
        float4 f1b = *(const float4*)&Lx[pb + ro1 + o2];
        bf16x8 Ah[2], Al[2];
        cvt8(f0a, f0b, Ah[0], Al[0]);
        cvt8(f1a, f1b, Ah[1], Al[1]);

        #pragma unroll
        for (int j = 0; j < 3; ++j)
            #pragma unroll
            for (int i = 0; i < 2; ++i) {
                acc[i][j] = __builtin_amdgcn_mfma_f32_16x16x32_bf16(Ah[i], bh[j], acc[i][j], 0, 0, 0);
                acc[i][j] = __builtin_amdgcn_mfma_f32_16x16x32_bf16(Al[i], bh[j], acc[i][j], 0, 0, 0);
                acc[i][j] = __builtin_amdgcn_mfma_f32_16x16x32_bf16(Ah[i], bl[j], acc[i][j], 0, 0, 0);
            }
        __syncthreads();
        p ^= 1;
    }

    #pragma unroll
    for (int j = 0; j < 3; ++j) {
        const int col = jbase + wct * 16 + 16 * j + l16;
        const float bj = bias[col];
        #pragma unroll
        for (int i = 0; i < 2; ++i) {
            float* yp = Y + (size_t)(rbase + wrow + i * 16 + quad * 4) * NPAD + col;
            yp[0 * NPAD] = acc[i][j][0] + bj;
            yp[1 * NPAD] = acc[i][j][1] + bj;
            yp[2 * NPAD] = acc[i][j][2] + bj;
            yp[3 * NPAD] = acc[i][j][3] + bj;
        }
    }
}

// ---------------------------------------------------------------------------
// Kernel 3: head. Block = 256 thr = 16 rows x 16 lanes (lane = class).
// ---------------------------------------------------------------------------
#define LROW 388   // padded LDS row stride (floats)

__global__ __launch_bounds__(256) void jcp_head3(const float* __restrict__ Y,
                                                 float* __restrict__ out) {
    __shared__ float Ly[16 * LROW];
    const int tid = threadIdx.x;
    const int r0  = blockIdx.x * 16;

    #pragma unroll
    for (int jj = 0; jj < 6; ++jj) {
        int f = tid + jj * 256;
        int row = f / 96, c4 = f - row * 96;
        float4 v = *(const float4*)(Y + (size_t)(r0 + row) * NPAD + c4 * 4);
        *(float4*)&Ly[row * LROW + c4 * 4] = v;
    }
    __syncthreads();

    const int grp = tid >> 4;
    const int c   = tid & 15;
    const bool on = (c < NCLS);
    const int r   = r0 + grp;
    const float* y = &Ly[grp * LROW];

    float y0c = on ? y[c] : -INFINITY;
    float m0 = y0c;
    #pragma unroll
    for (int m = 8; m >= 1; m >>= 1) m0 = fmaxf(m0, __shfl_xor(m0, m, 16));
    float e0 = on ? expf(y0c - m0) : 0.0f;
    float s0 = e0;
    #pragma unroll
    for (int m = 8; m >= 1; m >>= 1) s0 += __shfl_xor(s0, m, 16);
    const float Pc = e0 / s0;

    float v[NCLU];
    float mc = -INFINITY;
    #pragma unroll
    for (int k = 0; k < NCLU; ++k) {
        v[k] = y[12 + k * NCLS + c];
        mc = fmaxf(mc, v[k]);
    }
    float sc = 0.0f;
    #pragma unroll
    for (int k = 0; k < NCLU; ++k) sc += expf(v[k] - mc);
    const float rs = Pc / sc;

    float y2c[NDIM];
    #pragma unroll
    for (int n = 0; n < NDIM; ++n) y2c[n] = y[300 + n * NCLS + c];

    float best = -INFINITY;
    int bk = 0;
    float* lrow = &Ly[grp * LROW];
    #pragma unroll
    for (int k = 0; k < NCLU; ++k) {
        const float p = expf(v[k] - mc) * rs;
        if (on) lrow[k * NCLS + c] = p;
        if (p > best) { best = p; bk = k; }
    }
    int flat = bk * NCLS + c;
    if (!on) { best = -INFINITY; flat = 1 << 30; }

    #pragma unroll
    for (int m = 8; m >= 1; m >>= 1) {
        const float op = __shfl_xor(best, m, 16);
        const int   of = __shfl_xor(flat, m, 16);
        if (op > best || (op == best && of < flat)) { best = op; flat = of; }
    }
    const int ic = flat % NCLS;

    if (on) out[OUT0_OFF + (size_t)r * NCLS + c] = y0c;
    if (c == ic) {
        float* o1 = out + OUT1_OFF + (size_t)r * NCLU;
        #pragma unroll
        for (int k = 0; k < NCLU; ++k) o1[k] = v[k];
        float* o2 = out + OUT2_OFF + (size_t)r * NDIM;
        #pragma unroll
        for (int n = 0; n < NDIM; ++n) o2[n] = y2c[n];
    }

    __syncthreads();
    #pragma unroll
    for (int jj = 0; jj < 5; ++jj) {
        int f = tid + jj * 256;
        if (f < 1152) {
            int row = f / 72, c4 = f - row * 72;
            *(float4*)(out + OUT3_OFF + (size_t)(r0 + row) * (NCLU * NCLS) + c4 * 4) =
                *(float4*)&Ly[row * LROW + c4 * 4];
        }
    }
}

// ---------------------------------------------------------------------------
extern "C" void kernel_launch(void* const* d_in, const int* in_sizes, int n_in,
                              void* d_out, int out_size, void* d_ws, size_t ws_size,
                              hipStream_t stream) {
    const float* x     = (const float*)d_in[0];
    const float* W_fc  = (const float*)d_in[1];
    const float* b_fc  = (const float*)d_in[2];
    const float* W_bin = (const float*)d_in[3];
    const float* b_bin = (const float*)d_in[4];
    const float* W_res = (const float*)d_in[5];
    const float* b_res = (const float*)d_in[6];
    float* out = (float*)d_out;

    // ws layout (bytes):
    //   Bph 1.5MB | Bpl 1.5MB | bias 1.5KB | Y 25.2MB | Xc 134.2MB (fast path)
    ushort_t* Bph  = (ushort_t*)d_ws;                  // 24*64*64*8 bf16 = 1.5 MB
    ushort_t* Bpl  = Bph + NTILE * 64 * 64 * 8;        // 1.5 MB
    float*    bias = (float*)(Bpl + NTILE * 64 * 64 * 8);
    float*    Yb   = bias + NPAD;                      // 16384*384 fp32
    ushort_t* Xc   = (ushort_t*)(Yb + (size_t)BROWS * NPAD);  // 16384*4096 bf16*2 planes

    const size_t need = (size_t)(NTILE * 64 * 64 * 8) * 2 * sizeof(ushort_t)
                      + NPAD * sizeof(float)
                      + (size_t)BROWS * NPAD * sizeof(float)
                      + (size_t)BROWS * 4096 * sizeof(ushort_t);

    jcp_repack3<<<384, 256, 0, stream>>>(W_fc, b_fc, W_bin, b_bin, W_res, b_res,
                                         Bph, Bpl, bias);
    if (ws_size >= need) {
        jcp_xcvt<<<4096, 256, 0, stream>>>(x, Xc);
        jcp_gemm7<<<512, 256, 0, stream>>>(Xc, Bph, Bpl, bias, Yb);
    } else {
        dim3 grid(NPAD / 96, BROWS / 64);   // (4, 256)
        jcp_gemm4<<<grid, 256, 0, stream>>>(x, Bph, Bpl, bias, Yb);
    }
    jcp_head3<<<BROWS / 16, 256, 0, stream>>>(Yb, out);
}

// Round 4
// 280.313 us; speedup vs baseline: 1.4370x; 1.1786x over previous
//
#include <hip/hip_runtime.h>
#include <math.h>

// Problem constants
#define BROWS 16384
#define N0    2048
#define NCLS  12
#define NCLU  24
#define NDIM  4
#define NCOL  348          // 12 + 288 + 48
#define NPAD  384          // padded fused-column count (24 col-tiles of 16)
#define NTILE 24           // NPAD/16

// Output offsets (floats): y0 [B,12] | y1_sel [B,24] | y2_sel [B,4] | Plc [B,24,12]
#define OUT0_OFF 0
#define OUT1_OFF (BROWS * NCLS)
#define OUT2_OFF (OUT1_OFF + BROWS * NCLU)
#define OUT3_OFF (OUT2_OFF + BROWS * NDIM)

typedef __attribute__((ext_vector_type(8))) short bf16x8;
typedef __attribute__((ext_vector_type(4))) float f32x4;
typedef unsigned short ushort_t;

// ---------------------------------------------------------------------------
// bf16 helpers — RNE split (bit-identical to the passing numerics)
// ---------------------------------------------------------------------------
__device__ __forceinline__ unsigned short f2bf(float f) {   // RNE
    unsigned u = __float_as_uint(f);
    u += 0x7fffu + ((u >> 16) & 1u);
    return (unsigned short)(u >> 16);
}
__device__ __forceinline__ float bf2f(unsigned short h) {
    return __uint_as_float(((unsigned)h) << 16);
}
__device__ __forceinline__ void cvt8(float4 a, float4 b, bf16x8& h, bf16x8& l) {
    float f[8] = {a.x, a.y, a.z, a.w, b.x, b.y, b.z, b.w};
    #pragma unroll
    for (int i = 0; i < 8; ++i) {
        unsigned short hi = f2bf(f[i]);
        h[i] = (short)hi;
        l[i] = (short)f2bf(f[i] - bf2f(hi));
    }
}

__device__ __forceinline__ void load_lds16(const void* g, void* l) {
    __builtin_amdgcn_global_load_lds((const __attribute__((address_space(1))) void*)g,
                                     (__attribute__((address_space(3))) void*)l, 16, 0, 0);
}

__device__ __forceinline__ float fused_w(const float* __restrict__ W_fc,
                                         const float* __restrict__ W_bin,
                                         const float* __restrict__ W_res,
                                         int col, int d) {
    float w = 0.0f;
    if (col < NCLS) {
        w = W_fc[d * NCLS + col];
    } else if (col < 12 + NCLU * NCLS) {
        int jj = col - 12;
        int k = jj / NCLS, c = jj - k * NCLS;
        w = W_bin[((size_t)c * N0 + d) * NCLU + k];
    } else if (col < NCOL) {
        int jj = col - 300;
        int n = jj / NCLS, c = jj - n * NCLS;
        w = W_res[((size_t)c * N0 + d) * NDIM + n];
    }
    return w;
}

// ---------------------------------------------------------------------------
// Kernel 1: repack fused weights straight into MFMA-fragment streaming order.
//   Bp{h,l}[((J*64 + kb)*64 + lane)*8 + i] = W[col = J*16 + (lane&15)]
//                                             [k  = kb*32 + (lane>>4)*8 + i]
// ---------------------------------------------------------------------------
__global__ void jcp_repack3(const float* __restrict__ W_fc, const float* __restrict__ b_fc,
                            const float* __restrict__ W_bin, const float* __restrict__ b_bin,
                            const float* __restrict__ W_res, const float* __restrict__ b_res,
                            ushort_t* __restrict__ Bph, ushort_t* __restrict__ Bpl,
                            float* __restrict__ bias) {
    int t = blockIdx.x * 256 + threadIdx.x;          // 0 .. 98303
    if (t >= NTILE * 64 * 64) return;
    const int lane = t & 63;
    const int kb   = (t >> 6) & 63;
    const int J    = t >> 12;
    const int col  = J * 16 + (lane & 15);
    const int k0   = kb * 32 + (lane >> 4) * 8;

    bf16x8 h, l;
    #pragma unroll
    for (int i = 0; i < 8; ++i) {
        float w = fused_w(W_fc, W_bin, W_res, col, k0 + i);
        unsigned short hi = f2bf(w);
        h[i] = (short)hi;
        l[i] = (short)f2bf(w - bf2f(hi));
    }
    *(bf16x8*)(Bph + (size_t)t * 8) = h;
    *(bf16x8*)(Bpl + (size_t)t * 8) = l;

    if (t < NPAD) {
        int jb = t;
        float bv = 0.0f;
        if (jb < NCLS) {
            bv = b_fc[jb];
        } else if (jb < 12 + NCLU * NCLS) {
            int jj = jb - 12;
            int k = jj / NCLS, c = jj - k * NCLS;
            bv = b_bin[c * NCLU + k];
        } else if (jb < NCOL) {
            int jj = jb - 300;
            int n = jj / NCLS, c = jj - n * NCLS;
            bv = b_res[c * NDIM + n];
        }
        bias[jb] = bv;
    }
}

// ---------------------------------------------------------------------------
// Kernel 2: split-bf16 MFMA GEMM v8 — gemm7 skeleton + fused in-staging cvt.
//   Eliminates the jcp_xcvt pre-pass (134 MB write + 134 MB read of HBM).
//   Grid 512 (XCD-bijective: 128 row-panels x 4 col-blocks), block 256 = 4 waves.
//   Block tile: 128 rows x 96 cols; wave = 64x48 (4 row-tiles x 3 col-tiles,
//   36 MFMA/iter). 2 blocks/CU (LDS 56 KB).
//   x path (gemm4-proven): RAW fp32 -> LDS via global_load_lds (dbuf 2x16KB),
//     XOR chunk swizzle on the pre-swizzled global source; fragments read as
//     float4 pairs and cvt8'd in-register (1 cvt per element per block).
//   B path (gemm7-proven): Bp -> LDS DMA (dbuf 2x12KB), ds_read_b128 frags.
//   Pipeline (gemm7-proven): counted s_waitcnt vmcnt(7) + raw s_barrier;
//     the next buffer's 7 DMAs stay in flight across the barrier.
// ---------------------------------------------------------------------------
__global__ __launch_bounds__(256, 2) void jcp_gemm8(const float* __restrict__ x,
                                                    const ushort_t* __restrict__ Bph,
                                                    const ushort_t* __restrict__ Bpl,
                                                    const float* __restrict__ bias,
                                                    float* __restrict__ Y) {
    __shared__ float    Lx[2 * 4096];    // 2 bufs x 128 rows x 32 fp32 = 16 KB each
    __shared__ ushort_t Lb[2 * 6144];    // 2 bufs x 12 chunks x 512 ushorts = 12 KB each

    const int tid  = threadIdx.x;
    const int wid  = tid >> 6;
    const int lane = tid & 63;
    const int quad = lane >> 4;
    const int l16  = lane & 15;
    const int rg   = wid & 1;            // row half of block (64 rows)
    const int cg   = wid >> 1;           // col half of block (48 cols)

    // XCD-bijective decode: 4 col-blocks of a row-panel land on one XCD.
    const int g   = blockIdx.x;          // 0..511, 512 % 8 == 0 -> bijective
    const int xcd = g & 7;
    const int jj  = g >> 3;              // 0..63
    const int by  = xcd * 16 + (jj >> 2);
    const int bx  = jj & 3;
    const int rbase = by * 128;
    const int jbase = bx * 96;

    // --- x DMA (raw fp32): 4 insts/thread; inst n covers rows n*32 + (tid>>3),
    //     dest chunk tid&7 (16B units), source chunk XOR-swizzled by row. ---
    const int r0 = tid >> 3;             // 0..31
    const int c0 = tid & 7;
    const int o0 = c0 ^ (r0 & 7);        // pre-swizzled source chunk; (r0+32n)&7 == r0&7
    const float* gx = x + (size_t)(rbase + r0) * N0 + o0 * 4;   // + it*32 ; inst n: +n*65536
    // dest float offset: n*1024 + tid*4

    // --- B DMA: 3 insts/thread; wave w stages chunks w, 4+w, 8+w (1 KB each).
    const ushort_t* gb[3];
    int bdst[3];
    #pragma unroll
    for (int m = 0; m < 3; ++m) {
        const int c  = m * 4 + wid;                  // 0..11, wave-uniform
        const int J  = bx * 6 + (c >> 1);            // global col-tile 0..23
        const ushort_t* bp = (c & 1) ? Bpl : Bph;
        gb[m]   = bp + (size_t)J * 32768 + lane * 8; // + it*512 per iter
        bdst[m] = c * 512 + lane * 8;
    }

    // --- A fragment read offsets (floats), gemm4-proven swizzled layout ---
    const int s  = l16 & 7;
    const int o1 = ((2 * quad) ^ s) * 4;
    const int o2 = o1 ^ 4;

    f32x4 acc[4][3];
    #pragma unroll
    for (int rt = 0; rt < 4; ++rt)
        #pragma unroll
        for (int j = 0; j < 3; ++j)
            acc[rt][j] = f32x4{0.f, 0.f, 0.f, 0.f};

    // Prologue: issue buf0's 7 DMAs (it=0), then buf1's 7 (it=1).
    #pragma unroll
    for (int n = 0; n < 4; ++n) load_lds16(gx + n * 65536, &Lx[n * 1024 + tid * 4]);
    #pragma unroll
    for (int m = 0; m < 3; ++m) load_lds16(gb[m], &Lb[bdst[m]]);
    #pragma unroll
    for (int n = 0; n < 4; ++n) load_lds16(gx + n * 65536 + 32, &Lx[4096 + n * 1024 + tid * 4]);
    #pragma unroll
    for (int m = 0; m < 3; ++m) load_lds16(gb[m] + 512, &Lb[6144 + bdst[m]]);

    int p = 0;
    for (int it = 0; it < 63; ++it) {
        // Drain only this buffer's 7 loads; next buffer's 7 stay in flight.
        asm volatile("s_waitcnt vmcnt(7)" ::: "memory");
        asm volatile("s_barrier" ::: "memory");          // buf p ready (all waves)

        const float*    lx = &Lx[p * 4096];
        const ushort_t* lb = &Lb[p * 6144];

        // A fragments: fp32 float4 pairs from swizzled LDS -> cvt to hi/lo.
        float4 fa[4], fb[4];
        #pragma unroll
        for (int rt = 0; rt < 4; ++rt) {
            const int ro = (rg * 64 + rt * 16 + l16) * 32;
            fa[rt] = *(const float4*)&lx[ro + o1];
            fb[rt] = *(const float4*)&lx[ro + o2];
        }
        // B fragments: 6 x ds_read_b128 (3 col-tiles x hi/lo)
        bf16x8 bh[3], bl[3];
        #pragma unroll
        for (int j = 0; j < 3; ++j) {
            const int ch = (cg * 3 + j) * 2;
            bh[j] = *(const bf16x8*)(lb + ch * 512 + lane * 8);
            bl[j] = *(const bf16x8*)(lb + ch * 512 + 512 + lane * 8);
        }
        asm volatile("s_waitcnt lgkmcnt(0)" ::: "memory");   // frags in regs
        asm volatile("s_barrier" ::: "memory");              // all waves done reading p

        // Refill buf p for iteration it+2 (lands while we MFMA + next iter runs).
        if (it < 62) {
            #pragma unroll
            for (int n = 0; n < 4; ++n)
                load_lds16(gx + n * 65536 + (it + 2) * 32,
                           &Lx[p * 4096 + n * 1024 + tid * 4]);
            #pragma unroll
            for (int m = 0; m < 3; ++m)
                load_lds16(gb[m] + (it + 2) * 512, &Lb[p * 6144 + bdst[m]]);
        }

        // Convert A fragments (bit-identical split) — overlaps DMA issue.
        bf16x8 Ah[4], Al[4];
        #pragma unroll
        for (int rt = 0; rt < 4; ++rt) cvt8(fa[rt], fb[rt], Ah[rt], Al[rt]);

        // 36 MFMAs: per-accumulator order hh -> lh -> hl (bit-identical)
        __builtin_amdgcn_s_setprio(1);
        #pragma unroll
        for (int j = 0; j < 3; ++j)
            #pragma unroll
            for (int rt = 0; rt < 4; ++rt) {
                acc[rt][j] = __builtin_amdgcn_mfma_f32_16x16x32_bf16(Ah[rt], bh[j], acc[rt][j], 0, 0, 0);
                acc[rt][j] = __builtin_amdgcn_mfma_f32_16x16x32_bf16(Al[rt], bh[j], acc[rt][j], 0, 0, 0);
                acc[rt][j] = __builtin_amdgcn_mfma_f32_16x16x32_bf16(Ah[rt], bl[j], acc[rt][j], 0, 0, 0);
            }
        __builtin_amdgcn_s_setprio(0);
        p ^= 1;
    }

    // Peeled last iteration (it = 63, buf p): only its 7 loads remain.
    {
        asm volatile("s_waitcnt vmcnt(0)" ::: "memory");
        asm volatile("s_barrier" ::: "memory");
        const float*    lx = &Lx[p * 4096];
        const ushort_t* lb = &Lb[p * 6144];
        bf16x8 Ah[4], Al[4];
        #pragma unroll
        for (int rt = 0; rt < 4; ++rt) {
            const int ro = (rg * 64 + rt * 16 + l16) * 32;
            float4 fa = *(const float4*)&lx[ro + o1];
            float4 fb = *(const float4*)&lx[ro + o2];
            cvt8(fa, fb, Ah[rt], Al[rt]);
        }
        bf16x8 bh[3], bl[3];
        #pragma unroll
        for (int j = 0; j < 3; ++j) {
            const int ch = (cg * 3 + j) * 2;
            bh[j] = *(const bf16x8*)(lb + ch * 512 + lane * 8);
            bl[j] = *(const bf16x8*)(lb + ch * 512 + 512 + lane * 8);
        }
        #pragma unroll
        for (int j = 0; j < 3; ++j)
            #pragma unroll
            for (int rt = 0; rt < 4; ++rt) {
                acc[rt][j] = __builtin_amdgcn_mfma_f32_16x16x32_bf16(Ah[rt], bh[j], acc[rt][j], 0, 0, 0);
                acc[rt][j] = __builtin_amdgcn_mfma_f32_16x16x32_bf16(Al[rt], bh[j], acc[rt][j], 0, 0, 0);
                acc[rt][j] = __builtin_amdgcn_mfma_f32_16x16x32_bf16(Ah[rt], bl[j], acc[rt][j], 0, 0, 0);
            }
    }

    // Epilogue: C/D layout col = lane&15, row = quad*4 + reg
    #pragma unroll
    for (int j = 0; j < 3; ++j) {
        const int col = jbase + cg * 48 + 16 * j + l16;
        const float bj = bias[col];
        #pragma unroll
        for (int rt = 0; rt < 4; ++rt) {
            float* yp = Y + (size_t)(rbase + rg * 64 + rt * 16 + quad * 4) * NPAD + col;
            yp[0 * NPAD] = acc[rt][j][0] + bj;
            yp[1 * NPAD] = acc[rt][j][1] + bj;
            yp[2 * NPAD] = acc[rt][j][2] + bj;
            yp[3 * NPAD] = acc[rt][j][3] + bj;
        }
    }
}

// ---------------------------------------------------------------------------
// Kernel 3: head. Block = 256 thr = 16 rows x 16 lanes (lane = class).
// ---------------------------------------------------------------------------
#define LROW 388   // padded LDS row stride (floats)

__global__ __launch_bounds__(256) void jcp_head3(const float* __restrict__ Y,
                                                 float* __restrict__ out) {
    __shared__ float Ly[16 * LROW];
    const int tid = threadIdx.x;
    const int r0  = blockIdx.x * 16;

    #pragma unroll
    for (int jj = 0; jj < 6; ++jj) {
        int f = tid + jj * 256;
        int row = f / 96, c4 = f - row * 96;
        float4 v = *(const float4*)(Y + (size_t)(r0 + row) * NPAD + c4 * 4);
        *(float4*)&Ly[row * LROW + c4 * 4] = v;
    }
    __syncthreads();

    const int grp = tid >> 4;
    const int c   = tid & 15;
    const bool on = (c < NCLS);
    const int r   = r0 + grp;
    const float* y = &Ly[grp * LROW];

    float y0c = on ? y[c] : -INFINITY;
    float m0 = y0c;
    #pragma unroll
    for (int m = 8; m >= 1; m >>= 1) m0 = fmaxf(m0, __shfl_xor(m0, m, 16));
    float e0 = on ? expf(y0c - m0) : 0.0f;
    float s0 = e0;
    #pragma unroll
    for (int m = 8; m >= 1; m >>= 1) s0 += __shfl_xor(s0, m, 16);
    const float Pc = e0 / s0;

    float v[NCLU];
    float mc = -INFINITY;
    #pragma unroll
    for (int k = 0; k < NCLU; ++k) {
        v[k] = y[12 + k * NCLS + c];
        mc = fmaxf(mc, v[k]);
    }
    float sc = 0.0f;
    #pragma unroll
    for (int k = 0; k < NCLU; ++k) sc += expf(v[k] - mc);
    const float rs = Pc / sc;

    float y2c[NDIM];
    #pragma unroll
    for (int n = 0; n < NDIM; ++n) y2c[n] = y[300 + n * NCLS + c];

    float best = -INFINITY;
    int bk = 0;
    float* lrow = &Ly[grp * LROW];
    #pragma unroll
    for (int k = 0; k < NCLU; ++k) {
        const float p = expf(v[k] - mc) * rs;
        if (on) lrow[k * NCLS + c] = p;
        if (p > best) { best = p; bk = k; }
    }
    int flat = bk * NCLS + c;
    if (!on) { best = -INFINITY; flat = 1 << 30; }

    #pragma unroll
    for (int m = 8; m >= 1; m >>= 1) {
        const float op = __shfl_xor(best, m, 16);
        const int   of = __shfl_xor(flat, m, 16);
        if (op > best || (op == best && of < flat)) { best = op; flat = of; }
    }
    const int ic = flat % NCLS;

    if (on) out[OUT0_OFF + (size_t)r * NCLS + c] = y0c;
    if (c == ic) {
        float* o1 = out + OUT1_OFF + (size_t)r * NCLU;
        #pragma unroll
        for (int k = 0; k < NCLU; ++k) o1[k] = v[k];
        float* o2 = out + OUT2_OFF + (size_t)r * NDIM;
        #pragma unroll
        for (int n = 0; n < NDIM; ++n) o2[n] = y2c[n];
    }

    __syncthreads();
    #pragma unroll
    for (int jj = 0; jj < 5; ++jj) {
        int f = tid + jj * 256;
        if (f < 1152) {
            int row = f / 72, c4 = f - row * 72;
            *(float4*)(out + OUT3_OFF + (size_t)(r0 + row) * (NCLU * NCLS) + c4 * 4) =
                *(float4*)&Ly[row * LROW + c4 * 4];
        }
    }
}

// ---------------------------------------------------------------------------
extern "C" void kernel_launch(void* const* d_in, const int* in_sizes, int n_in,
                              void* d_out, int out_size, void* d_ws, size_t ws_size,
                              hipStream_t stream) {
    const float* x     = (const float*)d_in[0];
    const float* W_fc  = (const float*)d_in[1];
    const float* b_fc  = (const float*)d_in[2];
    const float* W_bin = (const float*)d_in[3];
    const float* b_bin = (const float*)d_in[4];
    const float* W_res = (const float*)d_in[5];
    const float* b_res = (const float*)d_in[6];
    float* out = (float*)d_out;

    // ws layout (bytes): Bph 1.5MB | Bpl 1.5MB | bias 1.5KB | Y 25.2MB
    ushort_t* Bph  = (ushort_t*)d_ws;                  // 24*64*64*8 bf16 = 1.5 MB
    ushort_t* Bpl  = Bph + NTILE * 64 * 64 * 8;        // 1.5 MB
    float*    bias = (float*)(Bpl + NTILE * 64 * 64 * 8);
    float*    Yb   = bias + NPAD;                      // 16384*384 fp32

    jcp_repack3<<<384, 256, 0, stream>>>(W_fc, b_fc, W_bin, b_bin, W_res, b_res,
                                         Bph, Bpl, bias);
    jcp_gemm8<<<512, 256, 0, stream>>>(x, Bph, Bpl, bias, Yb);
    jcp_head3<<<BROWS / 16, 256, 0, stream>>>(Yb, out);
}

// Round 5
// 268.143 us; speedup vs baseline: 1.5022x; 1.0454x over previous
//
#include <hip/hip_runtime.h>
#include <math.h>

// Problem constants
#define BROWS 16384
#define N0    2048
#define NCLS  12
#define NCLU  24
#define NDIM  4
#define NCOL  348          // 12 + 288 + 48
#define NPAD  384          // padded fused-column count (24 col-tiles of 16)
#define NTILE 24           // NPAD/16

// Output offsets (floats): y0 [B,12] | y1_sel [B,24] | y2_sel [B,4] | Plc [B,24,12]
#define OUT0_OFF 0
#define OUT1_OFF (BROWS * NCLS)
#define OUT2_OFF (OUT1_OFF + BROWS * NCLU)
#define OUT3_OFF (OUT2_OFF + BROWS * NDIM)

typedef __attribute__((ext_vector_type(8))) short bf16x8;
typedef __attribute__((ext_vector_type(4))) float f32x4;
typedef unsigned short ushort_t;

// ---------------------------------------------------------------------------
// bf16 helpers — RNE split (bit-identical to the passing numerics)
// ---------------------------------------------------------------------------
__device__ __forceinline__ unsigned short f2bf(float f) {   // RNE
    unsigned u = __float_as_uint(f);
    u += 0x7fffu + ((u >> 16) & 1u);
    return (unsigned short)(u >> 16);
}
__device__ __forceinline__ float bf2f(unsigned short h) {
    return __uint_as_float(((unsigned)h) << 16);
}
__device__ __forceinline__ void cvt8(float4 a, float4 b, bf16x8& h, bf16x8& l) {
    float f[8] = {a.x, a.y, a.z, a.w, b.x, b.y, b.z, b.w};
    #pragma unroll
    for (int i = 0; i < 8; ++i) {
        unsigned short hi = f2bf(f[i]);
        h[i] = (short)hi;
        l[i] = (short)f2bf(f[i] - bf2f(hi));
    }
}

// Packed-HW variant: v_cvt_pk_bf16_f32 is RNE — bit-identical to cvt8, ~3x
// fewer VALU ops. No builtin on gfx950 (m240) -> inline asm (T12 recipe).
__device__ __forceinline__ void cvt8pk(float4 a, float4 b, bf16x8& h, bf16x8& l) {
    unsigned h0, h1, h2, h3;
    asm("v_cvt_pk_bf16_f32 %0, %1, %2" : "=v"(h0) : "v"(a.x), "v"(a.y));
    asm("v_cvt_pk_bf16_f32 %0, %1, %2" : "=v"(h1) : "v"(a.z), "v"(a.w));
    asm("v_cvt_pk_bf16_f32 %0, %1, %2" : "=v"(h2) : "v"(b.x), "v"(b.y));
    asm("v_cvt_pk_bf16_f32 %0, %1, %2" : "=v"(h3) : "v"(b.z), "v"(b.w));
    // lo-plane residuals: exact fp32 subtraction of the hi bf16 value
    float r0 = a.x - __uint_as_float(h0 << 16);
    float r1 = a.y - __uint_as_float(h0 & 0xffff0000u);
    float r2 = a.z - __uint_as_float(h1 << 16);
    float r3 = a.w - __uint_as_float(h1 & 0xffff0000u);
    float r4 = b.x - __uint_as_float(h2 << 16);
    float r5 = b.y - __uint_as_float(h2 & 0xffff0000u);
    float r6 = b.z - __uint_as_float(h3 << 16);
    float r7 = b.w - __uint_as_float(h3 & 0xffff0000u);
    unsigned l0, l1, l2, l3;
    asm("v_cvt_pk_bf16_f32 %0, %1, %2" : "=v"(l0) : "v"(r0), "v"(r1));
    asm("v_cvt_pk_bf16_f32 %0, %1, %2" : "=v"(l1) : "v"(r2), "v"(r3));
    asm("v_cvt_pk_bf16_f32 %0, %1, %2" : "=v"(l2) : "v"(r4), "v"(r5));
    asm("v_cvt_pk_bf16_f32 %0, %1, %2" : "=v"(l3) : "v"(r6), "v"(r7));
    union Pack { unsigned u[4]; bf16x8 v; };
    Pack H; H.u[0] = h0; H.u[1] = h1; H.u[2] = h2; H.u[3] = h3;
    Pack L; L.u[0] = l0; L.u[1] = l1; L.u[2] = l2; L.u[3] = l3;
    h = H.v;
    l = L.v;
}

__device__ __forceinline__ void load_lds16(const void* g, void* l) {
    __builtin_amdgcn_global_load_lds((const __attribute__((address_space(1))) void*)g,
                                     (__attribute__((address_space(3))) void*)l, 16, 0, 0);
}

__device__ __forceinline__ float fused_w(const float* __restrict__ W_fc,
                                         const float* __restrict__ W_bin,
                                         const float* __restrict__ W_res,
                                         int col, int d) {
    float w = 0.0f;
    if (col < NCLS) {
        w = W_fc[d * NCLS + col];
    } else if (col < 12 + NCLU * NCLS) {
        int jj = col - 12;
        int k = jj / NCLS, c = jj - k * NCLS;
        w = W_bin[((size_t)c * N0 + d) * NCLU + k];
    } else if (col < NCOL) {
        int jj = col - 300;
        int n = jj / NCLS, c = jj - n * NCLS;
        w = W_res[((size_t)c * N0 + d) * NDIM + n];
    }
    return w;
}

// ---------------------------------------------------------------------------
// Kernel 1: repack fused weights straight into MFMA-fragment streaming order.
//   Bp{h,l}[((J*64 + kb)*64 + lane)*8 + i] = W[col = J*16 + (lane&15)]
//                                             [k  = kb*32 + (lane>>4)*8 + i]
// ---------------------------------------------------------------------------
__global__ void jcp_repack3(const float* __restrict__ W_fc, const float* __restrict__ b_fc,
                            const float* __restrict__ W_bin, const float* __restrict__ b_bin,
                            const float* __restrict__ W_res, const float* __restrict__ b_res,
                            ushort_t* __restrict__ Bph, ushort_t* __restrict__ Bpl,
                            float* __restrict__ bias) {
    int t = blockIdx.x * 256 + threadIdx.x;          // 0 .. 98303
    if (t >= NTILE * 64 * 64) return;
    const int lane = t & 63;
    const int kb   = (t >> 6) & 63;
    const int J    = t >> 12;
    const int col  = J * 16 + (lane & 15);
    const int k0   = kb * 32 + (lane >> 4) * 8;

    bf16x8 h, l;
    #pragma unroll
    for (int i = 0; i < 8; ++i) {
        float w = fused_w(W_fc, W_bin, W_res, col, k0 + i);
        unsigned short hi = f2bf(w);
        h[i] = (short)hi;
        l[i] = (short)f2bf(w - bf2f(hi));
    }
    *(bf16x8*)(Bph + (size_t)t * 8) = h;
    *(bf16x8*)(Bpl + (size_t)t * 8) = l;

    if (t < NPAD) {
        int jb = t;
        float bv = 0.0f;
        if (jb < NCLS) {
            bv = b_fc[jb];
        } else if (jb < 12 + NCLU * NCLS) {
            int jj = jb - 12;
            int k = jj / NCLS, c = jj - k * NCLS;
            bv = b_bin[c * NCLU + k];
        } else if (jb < NCOL) {
            int jj = jb - 300;
            int n = jj / NCLS, c = jj - n * NCLS;
            bv = b_res[c * NDIM + n];
        }
        bias[jb] = bv;
    }
}

// ---------------------------------------------------------------------------
// Kernel 2: split-bf16 MFMA GEMM v9 — gemm8 skeleton + packed HW cvt.
//   Grid 512 (XCD-bijective: 128 row-panels x 4 col-blocks), block 256 = 4 waves.
//   Block tile: 128 rows x 96 cols; wave = 64x48 (36 MFMA/iter). 2 blocks/CU.
//   x path: RAW fp32 -> LDS via global_load_lds (dbuf 2x16KB), XOR chunk
//     swizzle; fragments read as float4 pairs and cvt8pk'd in-register.
//   B path: Bp -> LDS DMA (dbuf 2x12KB), ds_read_b128 frags.
//   Pipeline: counted s_waitcnt vmcnt(7) + raw s_barrier (7 DMAs/buffer);
//     next buffer's 7 DMAs stay in flight across the barrier.
// ---------------------------------------------------------------------------
__global__ __launch_bounds__(256, 2) void jcp_gemm9(const float* __restrict__ x,
                                                    const ushort_t* __restrict__ Bph,
                                                    const ushort_t* __restrict__ Bpl,
                                                    const float* __restrict__ bias,
                                                    float* __restrict__ Y) {
    __shared__ float    Lx[2 * 4096];    // 2 bufs x 128 rows x 32 fp32 = 16 KB each
    __shared__ ushort_t Lb[2 * 6144];    // 2 bufs x 12 chunks x 512 ushorts = 12 KB each

    const int tid  = threadIdx.x;
    const int wid  = tid >> 6;
    const int lane = tid & 63;
    const int quad = lane >> 4;
    const int l16  = lane & 15;
    const int rg   = wid & 1;            // row half of block (64 rows)
    const int cg   = wid >> 1;           // col half of block (48 cols)

    // XCD-bijective decode: 4 col-blocks of a row-panel land on one XCD.
    const int g   = blockIdx.x;          // 0..511, 512 % 8 == 0 -> bijective
    const int xcd = g & 7;
    const int jj  = g >> 3;              // 0..63
    const int by  = xcd * 16 + (jj >> 2);
    const int bx  = jj & 3;
    const int rbase = by * 128;
    const int jbase = bx * 96;

    // --- x DMA (raw fp32): 4 insts/thread; inst n covers rows n*32 + (tid>>3),
    //     dest chunk tid&7 (16B units), source chunk XOR-swizzled by row. ---
    const int r0 = tid >> 3;             // 0..31
    const int c0 = tid & 7;
    const int o0 = c0 ^ (r0 & 7);        // pre-swizzled source chunk; (r0+32n)&7 == r0&7
    const float* gx = x + (size_t)(rbase + r0) * N0 + o0 * 4;   // + it*32 ; inst n: +n*65536
    // dest float offset: n*1024 + tid*4

    // --- B DMA: 3 insts/thread; wave w stages chunks w, 4+w, 8+w (1 KB each).
    const ushort_t* gb[3];
    int bdst[3];
    #pragma unroll
    for (int m = 0; m < 3; ++m) {
        const int c  = m * 4 + wid;                  // 0..11, wave-uniform
        const int J  = bx * 6 + (c >> 1);            // global col-tile 0..23
        const ushort_t* bp = (c & 1) ? Bpl : Bph;
        gb[m]   = bp + (size_t)J * 32768 + lane * 8; // + it*512 per iter
        bdst[m] = c * 512 + lane * 8;
    }

    // --- A fragment read offsets (floats), gemm4-proven swizzled layout ---
    const int s  = l16 & 7;
    const int o1 = ((2 * quad) ^ s) * 4;
    const int o2 = o1 ^ 4;

    f32x4 acc[4][3];
    #pragma unroll
    for (int rt = 0; rt < 4; ++rt)
        #pragma unroll
        for (int j = 0; j < 3; ++j)
            acc[rt][j] = f32x4{0.f, 0.f, 0.f, 0.f};

    // Prologue: issue buf0's 7 DMAs (it=0), then buf1's 7 (it=1).
    #pragma unroll
    for (int n = 0; n < 4; ++n) load_lds16(gx + n * 65536, &Lx[n * 1024 + tid * 4]);
    #pragma unroll
    for (int m = 0; m < 3; ++m) load_lds16(gb[m], &Lb[bdst[m]]);
    #pragma unroll
    for (int n = 0; n < 4; ++n) load_lds16(gx + n * 65536 + 32, &Lx[4096 + n * 1024 + tid * 4]);
    #pragma unroll
    for (int m = 0; m < 3; ++m) load_lds16(gb[m] + 512, &Lb[6144 + bdst[m]]);

    int p = 0;
    for (int it = 0; it < 63; ++it) {
        // Drain only this buffer's 7 loads; next buffer's 7 stay in flight.
        asm volatile("s_waitcnt vmcnt(7)" ::: "memory");
        asm volatile("s_barrier" ::: "memory");          // buf p ready (all waves)

        const float*    lx = &Lx[p * 4096];
        const ushort_t* lb = &Lb[p * 6144];

        // A fragments: fp32 float4 pairs from swizzled LDS -> cvt to hi/lo.
        float4 fa[4], fb[4];
        #pragma unroll
        for (int rt = 0; rt < 4; ++rt) {
            const int ro = (rg * 64 + rt * 16 + l16) * 32;
            fa[rt] = *(const float4*)&lx[ro + o1];
            fb[rt] = *(const float4*)&lx[ro + o2];
        }
        // B fragments: 6 x ds_read_b128 (3 col-tiles x hi/lo)
        bf16x8 bh[3], bl[3];
        #pragma unroll
        for (int j = 0; j < 3; ++j) {
            const int ch = (cg * 3 + j) * 2;
            bh[j] = *(const bf16x8*)(lb + ch * 512 + lane * 8);
            bl[j] = *(const bf16x8*)(lb + ch * 512 + 512 + lane * 8);
        }
        asm volatile("s_waitcnt lgkmcnt(0)" ::: "memory");   // frags in regs
        asm volatile("s_barrier" ::: "memory");              // all waves done reading p

        // Refill buf p for iteration it+2 (lands while we MFMA + next iter runs).
        if (it < 62) {
            #pragma unroll
            for (int n = 0; n < 4; ++n)
                load_lds16(gx + n * 65536 + (it + 2) * 32,
                           &Lx[p * 4096 + n * 1024 + tid * 4]);
            #pragma unroll
            for (int m = 0; m < 3; ++m)
                load_lds16(gb[m] + (it + 2) * 512, &Lb[p * 6144 + bdst[m]]);
        }

        // Convert A fragments (packed HW cvt, bit-identical) — overlaps DMA issue.
        bf16x8 Ah[4], Al[4];
        #pragma unroll
        for (int rt = 0; rt < 4; ++rt) cvt8pk(fa[rt], fb[rt], Ah[rt], Al[rt]);

        // 36 MFMAs: per-accumulator order hh -> lh -> hl (bit-identical)
        __builtin_amdgcn_s_setprio(1);
        #pragma unroll
        for (int j = 0; j < 3; ++j)
            #pragma unroll
            for (int rt = 0; rt < 4; ++rt) {
                acc[rt][j] = __builtin_amdgcn_mfma_f32_16x16x32_bf16(Ah[rt], bh[j], acc[rt][j], 0, 0, 0);
                acc[rt][j] = __builtin_amdgcn_mfma_f32_16x16x32_bf16(Al[rt], bh[j], acc[rt][j], 0, 0, 0);
                acc[rt][j] = __builtin_amdgcn_mfma_f32_16x16x32_bf16(Ah[rt], bl[j], acc[rt][j], 0, 0, 0);
            }
        __builtin_amdgcn_s_setprio(0);
        p ^= 1;
    }

    // Peeled last iteration (buf p): only its 7 loads remain.
    {
        asm volatile("s_waitcnt vmcnt(0)" ::: "memory");
        asm volatile("s_barrier" ::: "memory");
        const float*    lx = &Lx[p * 4096];
        const ushort_t* lb = &Lb[p * 6144];
        bf16x8 Ah[4], Al[4];
        #pragma unroll
        for (int rt = 0; rt < 4; ++rt) {
            const int ro = (rg * 64 + rt * 16 + l16) * 32;
            float4 fa = *(const float4*)&lx[ro + o1];
            float4 fb = *(const float4*)&lx[ro + o2];
            cvt8pk(fa, fb, Ah[rt], Al[rt]);
        }
        bf16x8 bh[3], bl[3];
        #pragma unroll
        for (int j = 0; j < 3; ++j) {
            const int ch = (cg * 3 + j) * 2;
            bh[j] = *(const bf16x8*)(lb + ch * 512 + lane * 8);
            bl[j] = *(const bf16x8*)(lb + ch * 512 + 512 + lane * 8);
        }
        #pragma unroll
        for (int j = 0; j < 3; ++j)
            #pragma unroll
            for (int rt = 0; rt < 4; ++rt) {
                acc[rt][j] = __builtin_amdgcn_mfma_f32_16x16x32_bf16(Ah[rt], bh[j], acc[rt][j], 0, 0, 0);
                acc[rt][j] = __builtin_amdgcn_mfma_f32_16x16x32_bf16(Al[rt], bh[j], acc[rt][j], 0, 0, 0);
                acc[rt][j] = __builtin_amdgcn_mfma_f32_16x16x32_bf16(Ah[rt], bl[j], acc[rt][j], 0, 0, 0);
            }
    }

    // Epilogue: C/D layout col = lane&15, row = quad*4 + reg
    #pragma unroll
    for (int j = 0; j < 3; ++j) {
        const int col = jbase + cg * 48 + 16 * j + l16;
        const float bj = bias[col];
        #pragma unroll
        for (int rt = 0; rt < 4; ++rt) {
            float* yp = Y + (size_t)(rbase + rg * 64 + rt * 16 + quad * 4) * NPAD + col;
            yp[0 * NPAD] = acc[rt][j][0] + bj;
            yp[1 * NPAD] = acc[rt][j][1] + bj;
            yp[2 * NPAD] = acc[rt][j][2] + bj;
            yp[3 * NPAD] = acc[rt][j][3] + bj;
        }
    }
}

// ---------------------------------------------------------------------------
// Kernel 3: head v4. Block = 256 thr = 16 rows x 16 lanes (lane = class).
//   Change vs v3: ev[k] computed once (expf was evaluated twice per k).
// ---------------------------------------------------------------------------
#define LROW 388   // padded LDS row stride (floats)

__global__ __launch_bounds__(256) void jcp_head4(const float* __restrict__ Y,
                                                 float* __restrict__ out) {
    __shared__ float Ly[16 * LROW];
    const int tid = threadIdx.x;
    const int r0  = blockIdx.x * 16;

    #pragma unroll
    for (int jj = 0; jj < 6; ++jj) {
        int f = tid + jj * 256;
        int row = f / 96, c4 = f - row * 96;
        float4 v = *(const float4*)(Y + (size_t)(r0 + row) * NPAD + c4 * 4);
        *(float4*)&Ly[row * LROW + c4 * 4] = v;
    }
    __syncthreads();

    const int grp = tid >> 4;
    const int c   = tid & 15;
    const bool on = (c < NCLS);
    const int r   = r0 + grp;
    const float* y = &Ly[grp * LROW];

    float y0c = on ? y[c] : -INFINITY;
    float m0 = y0c;
    #pragma unroll
    for (int m = 8; m >= 1; m >>= 1) m0 = fmaxf(m0, __shfl_xor(m0, m, 16));
    float e0 = on ? expf(y0c - m0) : 0.0f;
    float s0 = e0;
    #pragma unroll
    for (int m = 8; m >= 1; m >>= 1) s0 += __shfl_xor(s0, m, 16);
    const float Pc = e0 / s0;

    float v[NCLU];
    float mc = -INFINITY;
    #pragma unroll
    for (int k = 0; k < NCLU; ++k) {
        v[k] = y[12 + k * NCLS + c];
        mc = fmaxf(mc, v[k]);
    }
    float ev[NCLU];
    float sc = 0.0f;
    #pragma unroll
    for (int k = 0; k < NCLU; ++k) { ev[k] = expf(v[k] - mc); sc += ev[k]; }
    const float rs = Pc / sc;

    float y2c[NDIM];
    #pragma unroll
    for (int n = 0; n < NDIM; ++n) y2c[n] = y[300 + n * NCLS + c];

    float best = -INFINITY;
    int bk = 0;
    float* lrow = &Ly[grp * LROW];
    #pragma unroll
    for (int k = 0; k < NCLU; ++k) {
        const float p = ev[k] * rs;
        if (on) lrow[k * NCLS + c] = p;
        if (p > best) { best = p; bk = k; }
    }
    int flat = bk * NCLS + c;
    if (!on) { best = -INFINITY; flat = 1 << 30; }

    #pragma unroll
    for (int m = 8; m >= 1; m >>= 1) {
        const float op = __shfl_xor(best, m, 16);
        const int   of = __shfl_xor(flat, m, 16);
        if (op > best || (op == best && of < flat)) { best = op; flat = of; }
    }
    const int ic = flat % NCLS;

    if (on) out[OUT0_OFF + (size_t)r * NCLS + c] = y0c;
    if (c == ic) {
        float* o1 = out + OUT1_OFF + (size_t)r * NCLU;
        #pragma unroll
        for (int k = 0; k < NCLU; ++k) o1[k] = v[k];
        float* o2 = out + OUT2_OFF + (size_t)r * NDIM;
        #pragma unroll
        for (int n = 0; n < NDIM; ++n) o2[n] = y2c[n];
    }

    __syncthreads();
    #pragma unroll
    for (int jj = 0; jj < 5; ++jj) {
        int f = tid + jj * 256;
        if (f < 1152) {
            int row = f / 72, c4 = f - row * 72;
            *(float4*)(out + OUT3_OFF + (size_t)(r0 + row) * (NCLU * NCLS) + c4 * 4) =
                *(float4*)&Ly[row * LROW + c4 * 4];
        }
    }
}

// ---------------------------------------------------------------------------
extern "C" void kernel_launch(void* const* d_in, const int* in_sizes, int n_in,
                              void* d_out, int out_size, void* d_ws, size_t ws_size,
                              hipStream_t stream) {
    const float* x     = (const float*)d_in[0];
    const float* W_fc  = (const float*)d_in[1];
    const float* b_fc  = (const float*)d_in[2];
    const float* W_bin = (const float*)d_in[3];
    const float* b_bin = (const float*)d_in[4];
    const float* W_res = (const float*)d_in[5];
    const float* b_res = (const float*)d_in[6];
    float* out = (float*)d_out;

    // ws layout (bytes): Bph 1.5MB | Bpl 1.5MB | bias 1.5KB | Y 25.2MB
    ushort_t* Bph  = (ushort_t*)d_ws;                  // 24*64*64*8 bf16 = 1.5 MB
    ushort_t* Bpl  = Bph + NTILE * 64 * 64 * 8;        // 1.5 MB
    float*    bias = (float*)(Bpl + NTILE * 64 * 64 * 8);
    float*    Yb   = bias + NPAD;                      // 16384*384 fp32

    jcp_repack3<<<384, 256, 0, stream>>>(W_fc, b_fc, W_bin, b_bin, W_res, b_res,
                                         Bph, Bpl, bias);
    jcp_gemm9<<<512, 256, 0, stream>>>(x, Bph, Bpl, bias, Yb);
    jcp_head4<<<BROWS / 16, 256, 0, stream>>>(Yb, out);
}